// Round 9
// baseline (185.813 us; speedup 1.0000x reference)
//
#include <hip/hip_runtime.h>
#include <math.h>

#define T_TOK 2048
#define DM 1024
#define HQ 16
#define HD 64
#define NB 32
#define BS 64
#define S_SEL 16
#define NEGF (-1e30f)

typedef __attribute__((ext_vector_type(8))) short bf16x8;
typedef __attribute__((ext_vector_type(4))) float f32x4;
typedef unsigned short ush;

__device__ __forceinline__ ush f2bf(float x) {
  unsigned u = __float_as_uint(x);
  return (ush)((u + 0x7fffu + ((u >> 16) & 1u)) >> 16);
}
__device__ __forceinline__ float bf2f(ush h) {
  return __uint_as_float(((unsigned)h) << 16);
}

// ============================================================================
// Session-validated structure (R5 fragment-order attn + R8 XCD banding):
//   qbF[t]: idx = t*1024 + half*512 + quad*128 + head*8 + j
//   kbF[b]: idx = b*4096 + nc*1024 + half*512 + quad*128 + ck*8 + j
//   vbF[b]: idx = b*4096 + (p*4+dn)*512 + quad*128 + cd*8 + j
//   kcF:    idx = (nh*2+half)*512 + quad*128 + cf*8 + j
//   vtF:    idx = nb*512 + quad*128 + cf*8 + j
// R9: (a) split_w7 deleted — GEMMs split f32 A AND W inline during staging
// (identical hi/lo values -> bit-identical output; f32 fetch == plane fetch);
// (b) cmp+sel fused per-token: P/blkp/o_cmp live in LDS, ocmp becomes
// write-once; 5 dispatches -> 3.
// ============================================================================

// ---- split-bf16 MFMA GEMM body: Y = A @ W^T, 64x64 tile, BK=32 --------------
// A: f32 (Af, inline split) or bf16 planes (Ah_/Al_).
// W: f32 (Wf, inline split) or bf16 planes (Wh/Wl).
// ymode: 0 = f32/linear, 1 = Q-fragment, 2 = K-fragment, 3 = V-fragment
__device__ __forceinline__ void gemm64_body(
    const float* __restrict__ Af,
    const ush* __restrict__ Ah_, const ush* __restrict__ Al_,
    const float* __restrict__ Wf,
    const ush* __restrict__ Wh, const ush* __restrict__ Wl,
    float* Yf, ush* Yh, ush* Yl, int ymode, int useAtomic,
    ush* Ch, ush* Cl, int ctrans, int cidx, float (*cent)[64],
    int N, int K, int kStart, int kEnd, int m0, int n0,
    ush (*Ash)[40], ush (*Asl)[40], ush (*Bsh)[40], ush (*Bsl)[40])
{
  const int tid = threadIdx.x;
  const int wave = tid >> 6, lane = tid & 63;
  const int quad = lane >> 4, c16 = lane & 15;
  const int wm = wave >> 1, wn = wave & 1;
  const int ar = tid >> 2, ac = (tid & 3) * 8;
  f32x4 acc[2][2] = {};
  for (int k0 = kStart; k0 < kEnd; k0 += 32) {
    __syncthreads();
    if (Af) {
      const float* src = Af + (size_t)(m0 + ar) * K + k0 + ac;
      float4 u = *(const float4*)(src);
      float4 w2 = *(const float4*)(src + 4);
      float f[8] = {u.x, u.y, u.z, u.w, w2.x, w2.y, w2.z, w2.w};
      bf16x8 hv, lv;
      #pragma unroll
      for (int j = 0; j < 8; ++j) {
        ush hb = f2bf(f[j]);
        hv[j] = (short)hb;
        lv[j] = (short)f2bf(f[j] - bf2f(hb));
      }
      *(bf16x8*)&Ash[ar][ac] = hv;
      *(bf16x8*)&Asl[ar][ac] = lv;
    } else {
      *(bf16x8*)&Ash[ar][ac] = *(const bf16x8*)(Ah_ + (size_t)(m0 + ar) * K + k0 + ac);
      *(bf16x8*)&Asl[ar][ac] = *(const bf16x8*)(Al_ + (size_t)(m0 + ar) * K + k0 + ac);
    }
    if (Wf) {
      bf16x8 bh = {}, bl = {};
      if (n0 + ar < N) {
        const float* src = Wf + (size_t)(n0 + ar) * K + k0 + ac;
        float4 u = *(const float4*)(src);
        float4 w2 = *(const float4*)(src + 4);
        float f[8] = {u.x, u.y, u.z, u.w, w2.x, w2.y, w2.z, w2.w};
        #pragma unroll
        for (int j = 0; j < 8; ++j) {
          ush hb = f2bf(f[j]);
          bh[j] = (short)hb;
          bl[j] = (short)f2bf(f[j] - bf2f(hb));
        }
      }
      *(bf16x8*)&Bsh[ar][ac] = bh;
      *(bf16x8*)&Bsl[ar][ac] = bl;
    } else {
      bf16x8 bh = {}, bl = {};
      if (n0 + ar < N) {
        bh = *(const bf16x8*)(Wh + (size_t)(n0 + ar) * K + k0 + ac);
        bl = *(const bf16x8*)(Wl + (size_t)(n0 + ar) * K + k0 + ac);
      }
      *(bf16x8*)&Bsh[ar][ac] = bh;
      *(bf16x8*)&Bsl[ar][ac] = bl;
    }
    __syncthreads();
    bf16x8 Ahf[2], Alf[2], Bhf[2], Blf[2];
    #pragma unroll
    for (int mt = 0; mt < 2; ++mt) {
      Ahf[mt] = *(const bf16x8*)&Ash[wm*32 + mt*16 + c16][quad*8];
      Alf[mt] = *(const bf16x8*)&Asl[wm*32 + mt*16 + c16][quad*8];
    }
    #pragma unroll
    for (int nt = 0; nt < 2; ++nt) {
      Bhf[nt] = *(const bf16x8*)&Bsh[wn*32 + nt*16 + c16][quad*8];
      Blf[nt] = *(const bf16x8*)&Bsl[wn*32 + nt*16 + c16][quad*8];
    }
    #pragma unroll
    for (int mt = 0; mt < 2; ++mt)
      #pragma unroll
      for (int nt = 0; nt < 2; ++nt) {
        acc[mt][nt] = __builtin_amdgcn_mfma_f32_16x16x32_bf16(Ahf[mt], Bhf[nt], acc[mt][nt], 0, 0, 0);
        acc[mt][nt] = __builtin_amdgcn_mfma_f32_16x16x32_bf16(Ahf[mt], Blf[nt], acc[mt][nt], 0, 0, 0);
        acc[mt][nt] = __builtin_amdgcn_mfma_f32_16x16x32_bf16(Alf[mt], Bhf[nt], acc[mt][nt], 0, 0, 0);
      }
  }
  #pragma unroll
  for (int mt = 0; mt < 2; ++mt)
    #pragma unroll
    for (int nt = 0; nt < 2; ++nt) {
      int n = n0 + wn*32 + nt*16 + c16;
      if (n < N) {
        #pragma unroll
        for (int r = 0; r < 4; ++r) {
          int m = m0 + wm*32 + mt*16 + quad*4 + r;
          float vvv = acc[mt][nt][r];
          if (Yf) {
            if (useAtomic) atomicAdd(&Yf[(size_t)m*N + n], vvv);
            else Yf[(size_t)m*N + n] = vvv;
          }
          if (Yh) {
            ush hb = f2bf(vvv);
            size_t idx;
            if (ymode == 1) {              // Q-frag: t=m, h=n>>6, d=n&63
              int d = n & 63;
              idx = (size_t)m*1024 + (size_t)(d>>5)*512 + (size_t)((d>>3)&3)*128
                  + (size_t)(n>>6)*8 + (d&7);
            } else if (ymode == 2) {       // K-frag: key=m, d=n
              int b = m >> 6, kk = m & 63;
              idx = (size_t)b*4096 + (size_t)(kk>>4)*1024 + (size_t)(n>>5)*512
                  + (size_t)((n>>3)&3)*128 + (size_t)(kk&15)*8 + (n&7);
            } else if (ymode == 3) {       // V-frag: key=m, d=n
              int b = m >> 6, kk = m & 63, rem = kk & 31;
              idx = (size_t)b*4096 + (size_t)((kk>>5)*4 + (n>>4))*512
                  + (size_t)((rem>>2)&3)*128 + (size_t)(n&15)*8
                  + (rem&3) + ((rem>>4)&1)*4;
            } else {
              idx = (size_t)m*N + n;
            }
            Yh[idx] = hb;
            if (Yl) Yl[idx] = f2bf(vvv - bf2f(hb));
          }
        }
      }
    }
  if (Ch) {
    float ps[2];
    #pragma unroll
    for (int nt = 0; nt < 2; ++nt) {
      ps[nt] = 0.f;
      #pragma unroll
      for (int mt = 0; mt < 2; ++mt)
        #pragma unroll
        for (int r = 0; r < 4; ++r) ps[nt] += acc[mt][nt][r];
      ps[nt] += __shfl_xor(ps[nt], 16);
      ps[nt] += __shfl_xor(ps[nt], 32);
      if (quad == 0) cent[wm][wn*32 + nt*16 + c16] = ps[nt];
    }
    __syncthreads();
    if (wm == 0 && quad == 0) {
      #pragma unroll
      for (int nt = 0; nt < 2; ++nt) {
        int n = wn*32 + nt*16 + c16;
        float mval = (cent[0][n] + cent[1][n]) * (1.f/64.f);
        ush hb = f2bf(mval);
        ush lb = f2bf(mval - bf2f(hb));
        size_t idx;
        if (!ctrans) {   // K-centroid fragment: cent=cidx, d=n
          idx = (size_t)((cidx>>4)*2 + (n>>5))*512 + (size_t)((n>>3)&3)*128
              + (size_t)(cidx&15)*8 + (n&7);
        } else {         // V-centroid fragment: d=n, c=cidx
          idx = (size_t)(n>>4)*512 + (size_t)(cidx>>3)*128
              + (size_t)(n&15)*8 + (cidx&7);
        }
        Ch[idx] = hb; Cl[idx] = lb;
      }
    }
  }
}

// fused q/k/v/g projections from RAW f32 x and W (inline split; replaces
// split_w7), + grid-stride zero of `out` for gemm_out's atomics.
// 608 WGs, XCD-banded (R8-validated): XCD k <- by in [4k,4k+4) x all bx.
__global__ __launch_bounds__(256) void gemm_proj_f32(
    const float* __restrict__ x,
    const float* __restrict__ Wq, const float* __restrict__ Wk,
    const float* __restrict__ Wv, const float* __restrict__ Wg,
    ush* qbF, ush* qlF, ush* kbF, ush* vbF, float* gpj,
    ush* kcF, ush* kcFl, ush* vtF, ush* vtFl,
    float* __restrict__ outZ)
{
  __shared__ ush Ash[64][40], Asl[64][40], Bsh[64][40], Bsl[64][40];
  __shared__ float cent[2][64];
  // zero the out buffer (read later by gemm_out_f32 atomics); overlaps staging
  for (int idx = blockIdx.x*256 + threadIdx.x; idx < (T_TOK*DM)/4; idx += 608*256)
    ((float4*)outZ)[idx] = make_float4(0.f, 0.f, 0.f, 0.f);
  const int o = blockIdx.x;                  // 0..607
  const int s = (o & 7) * 76 + (o >> 3);     // chunked: XCD gets contiguous s
  const int local = s % 76;
  const int by = 4 * (s / 76) + local / 19;  // 0..31
  const int bx = local % 19;                 // 0..18
  if (bx < 16) {
    gemm64_body(x, nullptr, nullptr, Wq, nullptr, nullptr,
                nullptr, qbF, qlF, 1, 0,
                nullptr, nullptr, 0, 0, nullptr,
                DM, DM, 0, DM, by*64, bx*64, Ash, Asl, Bsh, Bsl);
  } else if (bx == 16) {
    gemm64_body(x, nullptr, nullptr, Wk, nullptr, nullptr,
                nullptr, kbF, nullptr, 2, 0,
                kcF, kcFl, 0, by, cent,
                HD, DM, 0, DM, by*64, 0, Ash, Asl, Bsh, Bsl);
  } else if (bx == 17) {
    gemm64_body(x, nullptr, nullptr, Wv, nullptr, nullptr,
                nullptr, vbF, nullptr, 3, 0,
                vtF, vtFl, 1, by, cent,
                HD, DM, 0, DM, by*64, 0, Ash, Asl, Bsh, Bsl);
  } else {
    gemm64_body(x, nullptr, nullptr, Wg, nullptr, nullptr,
                gpj, nullptr, nullptr, 0, 0,
                nullptr, nullptr, 0, 0, nullptr,
                48, DM, 0, DM, by*64, 0, Ash, Asl, Bsh, Bsl);
  }
}

// out-projection from f32 Wo (inline split); SPLIT-K=2 via f32 atomics.
// 1024 WGs = 8 x 128, XCD-banded (R8-validated).
__global__ __launch_bounds__(256) void gemm_out_f32(
    const float* __restrict__ Af, const float* __restrict__ Wo,
    float* Yf, int N, int K)
{
  __shared__ ush Ash[64][40], Asl[64][40], Bsh[64][40], Bsl[64][40];
  const int o = blockIdx.x;                  // 0..1023
  const int s = (o & 7) * 128 + (o >> 3);
  const int kz = s >> 9;                     // 0..1
  const int rem = s & 511;
  const int by = rem >> 4;                   // 0..31
  const int bx = rem & 15;                   // 0..15
  const int kHalf = K >> 1;
  const int kStart = kz * kHalf;
  gemm64_body(Af, nullptr, nullptr, Wo, nullptr, nullptr,
              Yf, nullptr, nullptr, 0, 1,
              nullptr, nullptr, 0, 0, nullptr,
              N, K, kStart, kStart + kHalf, by*64, bx*64,
              Ash, Asl, Bsh, Bsl);
}

// ---- FUSED compressed + selected attention: one WG per token ----------------
// Wave 0: cmp QK + softmax + serial top-k (bit-identical to R8's cmp_attn),
// publishing P (probs) and the 16 block indices to LDS. After one barrier:
// all 4 waves compute PV-cmp (one d-block each, into LDS ocs) AND their sel
// blocks (R5/R8 swapped-operand form, blkp from LDS). Final blend reads o_cmp
// from LDS and writes ocmp ONCE (was: cmp writes 8.4MB + sel RMWs it).
__global__ __launch_bounds__(256) void cmp_sel_fused(
    const ush* __restrict__ qbF, const ush* __restrict__ qlF,
    const ush* __restrict__ kcF, const ush* __restrict__ kcFl,
    const ush* __restrict__ vtF, const ush* __restrict__ vtFl,
    const ush* __restrict__ kbF, const ush* __restrict__ vbF,
    const float* __restrict__ gp, float* __restrict__ ocmp_out)
{
  __shared__ float Pls[16][36];     // cmp probs [h][cent]
  __shared__ float ocs[64][17];     // o_cmp [d][h]
  __shared__ int   blks[S_SEL];
  __shared__ float cO2[4][4][16][17];
  __shared__ float cL[4][16];

  const int tid = threadIdx.x, w = tid >> 6, lane = tid & 63;
  const int quad = lane >> 4, c16 = lane & 15;
  const int t = T_TOK - 1 - blockIdx.x;         // heavy tokens first
  const int cur = t >> 6;
  const int nblk = (cur + 1 < S_SEL) ? cur + 1 : S_SEL;

  // Q hi fragment (all waves: sel; wave 0 also cmp)
  const ush* qt = qbF + (size_t)t*DM + lane*8;
  bf16x8 qa0 = *(const bf16x8*)(qt);
  bf16x8 qa1 = *(const bf16x8*)(qt + 512);

  if (w == 0) {
    // ---- cmp: QK^T over 32 centroids (split-bf16), softmax, top-k ----
    const ush* ql = qlF + (size_t)t*DM + lane*8;
    bf16x8 qal0 = *(const bf16x8*)(ql);
    bf16x8 qal1 = *(const bf16x8*)(ql + 512);

    f32x4 s[2];
    #pragma unroll
    for (int nh = 0; nh < 2; ++nh) {
      bf16x8 kh0 = *(const bf16x8*)(kcF  + (nh*2+0)*512 + lane*8);
      bf16x8 kh1 = *(const bf16x8*)(kcF  + (nh*2+1)*512 + lane*8);
      bf16x8 kl0 = *(const bf16x8*)(kcFl + (nh*2+0)*512 + lane*8);
      bf16x8 kl1 = *(const bf16x8*)(kcFl + (nh*2+1)*512 + lane*8);
      f32x4 acc = {0.f, 0.f, 0.f, 0.f};
      acc = __builtin_amdgcn_mfma_f32_16x16x32_bf16(qa0, kh0, acc, 0, 0, 0);
      acc = __builtin_amdgcn_mfma_f32_16x16x32_bf16(qa1, kh1, acc, 0, 0, 0);
      acc = __builtin_amdgcn_mfma_f32_16x16x32_bf16(qa0, kl0, acc, 0, 0, 0);
      acc = __builtin_amdgcn_mfma_f32_16x16x32_bf16(qa1, kl1, acc, 0, 0, 0);
      acc = __builtin_amdgcn_mfma_f32_16x16x32_bf16(qal0, kh0, acc, 0, 0, 0);
      acc = __builtin_amdgcn_mfma_f32_16x16x32_bf16(qal1, kh1, acc, 0, 0, 0);
      s[nh] = acc;
    }

    const int nvis = (t + 1) >> 6;
    const bool visA = (c16 < nvis), visB = (16 + c16 < nvis);
    float p[2][4];
    float iA = 0.f, iB = 0.f;
    #pragma unroll
    for (int r = 0; r < 4; ++r) {
      float sA = s[0][r] * 0.125f, sB = s[1][r] * 0.125f;
      float m = fmaxf(visA ? sA : -INFINITY, visB ? sB : -INFINITY);
      #pragma unroll
      for (int off = 1; off < 16; off <<= 1) m = fmaxf(m, __shfl_xor(m, off));
      float eA = visA ? __expf(sA - m) : 0.f;
      float eB = visB ? __expf(sB - m) : 0.f;
      float l = eA + eB;
      #pragma unroll
      for (int off = 1; off < 16; off <<= 1) l += __shfl_xor(l, off);
      float inv = (l > 0.f) ? 1.f / l : 0.f;
      p[0][r] = eA * inv; p[1][r] = eB * inv;
      iA += p[0][r]; iB += p[1][r];
    }
    iA += __shfl_xor(iA, 16); iA += __shfl_xor(iA, 32);
    iB += __shfl_xor(iB, 16); iB += __shfl_xor(iB, 32);

    #pragma unroll
    for (int nh = 0; nh < 2; ++nh)
      #pragma unroll
      for (int r = 0; r < 4; ++r)
        Pls[quad*4 + r][nh*16 + c16] = p[nh][r];

    {
      float a;
      if (lane < 16) a = iA;
      else if (lane < 32) a = iB;
      else a = -INFINITY;
      if (lane < 32) {
        if (lane > cur) a = NEGF;
        if (lane == 0 || lane == cur) a = INFINITY;
      }
      for (int sidx = 0; sidx < S_SEL; ++sidx) {
        float bv = a; int bi = lane;
        #pragma unroll
        for (int off = 1; off < 64; off <<= 1) {
          float ov = __shfl_xor(bv, off); int oi = __shfl_xor(bi, off);
          if (ov > bv || (ov == bv && oi < bi)) { bv = ov; bi = oi; }
        }
        if (lane == 0) blks[sidx] = bi;
        if (lane == bi) a = -INFINITY;
      }
    }
  }
  __syncthreads();   // Pls + blks visible to all waves

  // ---- PV-cmp distributed: wave w computes d-block nb=w (3 MFMAs) ----
  {
    float4 pa = *(const float4*)&Pls[c16][quad*8];
    float4 pb = *(const float4*)&Pls[c16][quad*8 + 4];
    float pfv[8] = {pa.x, pa.y, pa.z, pa.w, pb.x, pb.y, pb.z, pb.w};
    bf16x8 pah, pal;
    #pragma unroll
    for (int j = 0; j < 8; ++j) {
      ush hb = f2bf(pfv[j]);
      pah[j] = (short)hb;
      pal[j] = (short)f2bf(pfv[j] - bf2f(hb));
    }
    bf16x8 vh8 = *(const bf16x8*)(vtF  + w*512 + lane*8);
    bf16x8 vl8 = *(const bf16x8*)(vtFl + w*512 + lane*8);
    f32x4 acc = {0.f, 0.f, 0.f, 0.f};
    acc = __builtin_amdgcn_mfma_f32_16x16x32_bf16(pah, vh8, acc, 0, 0, 0);
    acc = __builtin_amdgcn_mfma_f32_16x16x32_bf16(pah, vl8, acc, 0, 0, 0);
    acc = __builtin_amdgcn_mfma_f32_16x16x32_bf16(pal, vh8, acc, 0, 0, 0);
    #pragma unroll
    for (int r = 0; r < 4; ++r)
      ocs[w*16 + c16][quad*4 + r] = acc[r];   // d = w*16+c16, h = quad*4+r
  }

  // ---- sel blocks (R5/R8 form; block indices from LDS) ----
  const int nb_w = (nblk > w) ? (((nblk - 1 - w) >> 2) + 1) : 0;
  f32x4 accO[4] = {};
  float lacc = 0.f;

  for (int i = 0; i < nb_w; ++i) {
    const int blk = blks[w + (i << 2)];
    const int bs = blk * BS;
    const ush* kB = kbF + (size_t)blk * 4096 + lane*8;
    const ush* vB = vbF + (size_t)blk * 4096 + lane*8;

    bf16x8 kf0[4], kf1[4];
    #pragma unroll
    for (int nc = 0; nc < 4; ++nc) {
      kf0[nc] = *(const bf16x8*)(kB + nc*1024);
      kf1[nc] = *(const bf16x8*)(kB + nc*1024 + 512);
    }
    bf16x8 vf[4][2];
    #pragma unroll
    for (int p = 0; p < 2; ++p)
      #pragma unroll
      for (int dn = 0; dn < 4; ++dn)
        vf[dn][p] = *(const bf16x8*)(vB + (p*4 + dn)*512);

    f32x4 sc[4];
    #pragma unroll
    for (int nc = 0; nc < 4; ++nc) {
      f32x4 a = {0.f, 0.f, 0.f, 0.f};
      a = __builtin_amdgcn_mfma_f32_16x16x32_bf16(kf0[nc], qa0, a, 0, 0, 0);
      a = __builtin_amdgcn_mfma_f32_16x16x32_bf16(kf1[nc], qa1, a, 0, 0, 0);
      sc[nc] = a;
    }

    ush pf[16];
    #pragma unroll
    for (int nc = 0; nc < 4; ++nc) {
      const int k0 = bs + nc*16 + quad*4;
      #pragma unroll
      for (int r = 0; r < 4; ++r) {
        float e = (k0 + r <= t) ? __expf(sc[nc][r] * 0.125f) : 0.f;
        lacc += e;
        pf[nc*4 + r] = f2bf(e);
      }
    }
    bf16x8 P01, P23;
    #pragma unroll
    for (int j = 0; j < 8; ++j) {
      P01[j] = (short)pf[j];
      P23[j] = (short)pf[8 + j];
    }

    #pragma unroll
    for (int dn = 0; dn < 4; ++dn) {
      accO[dn] = __builtin_amdgcn_mfma_f32_16x16x32_bf16(vf[dn][0], P01, accO[dn], 0, 0, 0);
      accO[dn] = __builtin_amdgcn_mfma_f32_16x16x32_bf16(vf[dn][1], P23, accO[dn], 0, 0, 0);
    }
  }

  lacc += __shfl_xor(lacc, 16);
  lacc += __shfl_xor(lacc, 32);

  if (quad == 0) cL[w][c16] = lacc;
  #pragma unroll
  for (int dn = 0; dn < 4; ++dn)
    #pragma unroll
    for (int r = 0; r < 4; ++r)
      cO2[w][dn][quad*4 + r][c16] = accO[dn][r];
  __syncthreads();   // covers cO2/cL AND ocs writes

  // ---- blend + single coalesced write ----
  #pragma unroll
  for (int i = 0; i < 4; ++i) {
    const int h = i*4 + w;
    float L = cL[0][h] + cL[1][h] + cL[2][h] + cL[3][h];
    float O = cO2[0][quad][c16][h] + cO2[1][quad][c16][h]
            + cO2[2][quad][c16][h] + cO2[3][quad][c16][h];
    float oc = ocs[lane][h];
    float ga = gp[(size_t)t*48 + h*3 + 0];
    float gb = gp[(size_t)t*48 + h*3 + 1];
    float gcv = 1.f/(1.f + __expf(-ga));
    float gsv = 1.f/(1.f + __expf(-gb));
    ocmp_out[(size_t)t*DM + (size_t)h*HD + lane] = O * gsv / L + oc * gcv;
  }
}

extern "C" void kernel_launch(void* const* d_in, const int* in_sizes, int n_in,
                              void* d_out, int out_size, void* d_ws, size_t ws_size,
                              hipStream_t stream)
{
  const float* x  = (const float*)d_in[0];
  const float* Wq = (const float*)d_in[1];
  const float* Wk = (const float*)d_in[2];
  const float* Wv = (const float*)d_in[3];
  const float* Wg = (const float*)d_in[4];
  const float* Wo = (const float*)d_in[5];
  float* out = (float*)d_out;

  float* ws   = (float*)d_ws;
  float* gpj  = ws;                                // 2048*48 f32
  float* ocmp = gpj + (size_t)T_TOK*48;            // 2048*1024 f32 (combined o)
  ush* qbF = (ush*)(ocmp + (size_t)T_TOK*DM);      // Q fragment-order (hi)
  ush* qlF = qbF + (size_t)T_TOK*DM;               // Q fragment-order (lo)
  ush* kbF = qlF + (size_t)T_TOK*DM;               // K fragment-order (2048*64)
  ush* vbF = kbF + (size_t)T_TOK*HD;               // V fragment-order (2048*64)
  ush* kcF = vbF + (size_t)T_TOK*HD;
  ush* kcFl = kcF + NB*HD;
  ush* vtF = kcFl + NB*HD;
  ush* vtFl = vtF + NB*HD;

  gemm_proj_f32<<<608, 256, 0, stream>>>(x, Wq, Wk, Wv, Wg,
      qbF, qlF, kbF, vbF, gpj, kcF, kcFl, vtF, vtFl, out);
  cmp_sel_fused<<<T_TOK, 256, 0, stream>>>(qbF, qlF, kcF, kcFl, vtF, vtFl,
      kbF, vbF, gpj, ocmp);
  gemm_out_f32<<<1024, 256, 0, stream>>>(ocmp, Wo, out, DM, DM);
}

// Round 10
// 166.616 us; speedup vs baseline: 1.1152x; 1.1152x over previous
//
#include <hip/hip_runtime.h>
#include <math.h>

#define T_TOK 2048
#define DM 1024
#define HQ 16
#define HD 64
#define NB 32
#define BS 64
#define S_SEL 16
#define NEGF (-1e30f)

typedef __attribute__((ext_vector_type(8))) short bf16x8;
typedef __attribute__((ext_vector_type(4))) float f32x4;
typedef unsigned short ush;

#define AS3(p) ((__attribute__((address_space(3))) void*)(p))
#define AS1(p) ((const __attribute__((address_space(1))) void*)(p))

__device__ __forceinline__ ush f2bf(float x) {
  unsigned u = __float_as_uint(x);
  return (ush)((u + 0x7fffu + ((u >> 16) & 1u)) >> 16);
}
__device__ __forceinline__ float bf2f(ush h) {
  return __uint_as_float(((unsigned)h) << 16);
}

// ============================================================================
// R10 = exact R8 structure (best, 173.9us: split_w7 + plane GEMMs + XCD
// banding + separate cmp/sel fragment-order attn) + ONE change:
// global_load_lds width-16 async staging in the GEMM body (m193: +67% on
// staging-bound GEMMs — R9's counters showed proj staging-rate-bound at
// 780GB/s fill, 29% VALU).
//  - LDS tiles linear [64][32] ush (rule #21: gload_lds needs linear dest)
//  - 4-slot XOR swizzle (slot ^= row&3) applied on BOTH the pre-swizzled
//    global source and the fragment read (same involution)
//  - 1KB gload per tile per wave per k-step (was 16 loads + 16 ds_writes)
//  - gemm_out's f32 A keeps thread staging w/ swizzled stores (same conv.)
// R9 lessons: inline W-split (VALU chain in staging) and cmp/sel fusion
// (serial 1-wave cmp head) BOTH regressed — reverted.
// ============================================================================

// ---- decompose weights + x into bf16 hi/lo planes; seg 6 zeroes d_out -------
__global__ __launch_bounds__(256) void split_w7(
    const float* __restrict__ s0, const float* __restrict__ s1,
    const float* __restrict__ s2, const float* __restrict__ s3,
    const float* __restrict__ s4, const float* __restrict__ s5,
    ush* h0, ush* l0, ush* h1, ush* l1, ush* h2, ush* l2,
    ush* h3, ush* l3, ush* h4, ush* l4, ush* h5, ush* l5,
    float* __restrict__ zout)
{
  int seg = blockIdx.y;
  if (seg == 6) {
    int i = blockIdx.x * 256 + threadIdx.x;
    if (i < (T_TOK*DM)/4) ((float4*)zout)[i] = make_float4(0.f,0.f,0.f,0.f);
    return;
  }
  const float* srcs[6] = {s0, s1, s2, s3, s4, s5};
  ush* hs[6] = {h0, h1, h2, h3, h4, h5};
  ush* ls[6] = {l0, l1, l2, l3, l4, l5};
  const int ns[6] = {1048576, 65536, 65536, 49152, 1048576, 2097152};
  int i = (blockIdx.x * 256 + threadIdx.x) * 4;
  if (i >= ns[seg]) return;
  float4 v = *(const float4*)(srcs[seg] + i);
  ushort4 hv, lv;
  hv.x = f2bf(v.x); lv.x = f2bf(v.x - bf2f(hv.x));
  hv.y = f2bf(v.y); lv.y = f2bf(v.y - bf2f(hv.y));
  hv.z = f2bf(v.z); lv.z = f2bf(v.z - bf2f(hv.z));
  hv.w = f2bf(v.w); lv.w = f2bf(v.w - bf2f(hv.w));
  *(ushort4*)(hs[seg] + i) = hv;
  *(ushort4*)(ls[seg] + i) = lv;
}

// ---- split-bf16 MFMA GEMM body: Y = A @ W^T, 64x64 tile, BK=32 --------------
// LDS tiles: linear [64][32] ush; LDS(row, slot) holds global slot
// slot^(row&3) (slot = 8-ush group). A: f32 (Af, thread-staged inline split,
// swizzled stores) or bf16 planes (gload_lds). B: always planes (gload_lds).
// ymode: 0 = f32/linear, 1 = Q-fragment, 2 = K-fragment, 3 = V-fragment
__device__ __forceinline__ void gemm64_body(
    const float* __restrict__ Af,
    const ush* __restrict__ Ah_, const ush* __restrict__ Al_,
    const ush* __restrict__ Wh, const ush* __restrict__ Wl,
    float* Yf, ush* Yh, ush* Yl, int ymode, int useAtomic,
    ush* Ch, ush* Cl, int ctrans, int cidx, float (*cent)[64],
    int N, int K, int kStart, int kEnd, int m0, int n0,
    ush* Ash, ush* Asl, ush* Bsh, ush* Bsl)
{
  const int tid = threadIdx.x;
  const int wave = tid >> 6, lane = tid & 63;
  const int quad = lane >> 4, c16 = lane & 15;
  const int wm = wave >> 1, wn = wave & 1;
  // gload staging geometry: wave stages 16 rows; lane -> (row, slot)
  const int srow_l = wave*16 + (lane >> 2);          // 0..63
  const int sslot  = lane & 3;
  const int sw_slot = sslot ^ (srow_l & 3);          // pre-swizzled src slot
  const size_t gsA = (size_t)(m0 + srow_l) * K + sw_slot*8;
  const size_t gsB = (size_t)(n0 + srow_l) * K + sw_slot*8;
  f32x4 acc[2][2] = {};
  for (int k0 = kStart; k0 < kEnd; k0 += 32) {
    __syncthreads();
    if (Af) {
      const int ar = tid >> 2, j = tid & 3;
      const float* src = Af + (size_t)(m0 + ar) * K + k0 + j*8;
      float4 u = *(const float4*)(src);
      float4 w2 = *(const float4*)(src + 4);
      float f[8] = {u.x, u.y, u.z, u.w, w2.x, w2.y, w2.z, w2.w};
      bf16x8 hv, lv;
      #pragma unroll
      for (int jj = 0; jj < 8; ++jj) {
        ush hb = f2bf(f[jj]);
        hv[jj] = (short)hb;
        lv[jj] = (short)f2bf(f[jj] - bf2f(hb));
      }
      const int soff = ar*32 + ((j ^ (ar & 3)) * 8); // swizzled store
      *(bf16x8*)&Ash[soff] = hv;
      *(bf16x8*)&Asl[soff] = lv;
    } else {
      __builtin_amdgcn_global_load_lds(AS1(Ah_ + gsA + k0), AS3(Ash + wave*512), 16, 0, 0);
      __builtin_amdgcn_global_load_lds(AS1(Al_ + gsA + k0), AS3(Asl + wave*512), 16, 0, 0);
    }
    __builtin_amdgcn_global_load_lds(AS1(Wh + gsB + k0), AS3(Bsh + wave*512), 16, 0, 0);
    __builtin_amdgcn_global_load_lds(AS1(Wl + gsB + k0), AS3(Bsl + wave*512), 16, 0, 0);
    __syncthreads();
    bf16x8 Ahf[2], Alf[2], Bhf[2], Blf[2];
    const int rslot = (quad ^ (c16 & 3)) * 8;        // swizzled read slot
    #pragma unroll
    for (int mt = 0; mt < 2; ++mt) {
      const int ro = (wm*32 + mt*16 + c16)*32 + rslot;
      Ahf[mt] = *(const bf16x8*)&Ash[ro];
      Alf[mt] = *(const bf16x8*)&Asl[ro];
    }
    #pragma unroll
    for (int nt = 0; nt < 2; ++nt) {
      const int ro = (wn*32 + nt*16 + c16)*32 + rslot;
      Bhf[nt] = *(const bf16x8*)&Bsh[ro];
      Blf[nt] = *(const bf16x8*)&Bsl[ro];
    }
    #pragma unroll
    for (int mt = 0; mt < 2; ++mt)
      #pragma unroll
      for (int nt = 0; nt < 2; ++nt) {
        acc[mt][nt] = __builtin_amdgcn_mfma_f32_16x16x32_bf16(Ahf[mt], Bhf[nt], acc[mt][nt], 0, 0, 0);
        acc[mt][nt] = __builtin_amdgcn_mfma_f32_16x16x32_bf16(Ahf[mt], Blf[nt], acc[mt][nt], 0, 0, 0);
        acc[mt][nt] = __builtin_amdgcn_mfma_f32_16x16x32_bf16(Alf[mt], Bhf[nt], acc[mt][nt], 0, 0, 0);
      }
  }
  #pragma unroll
  for (int mt = 0; mt < 2; ++mt)
    #pragma unroll
    for (int nt = 0; nt < 2; ++nt) {
      int n = n0 + wn*32 + nt*16 + c16;
      if (n < N) {
        #pragma unroll
        for (int r = 0; r < 4; ++r) {
          int m = m0 + wm*32 + mt*16 + quad*4 + r;
          float vvv = acc[mt][nt][r];
          if (Yf) {
            if (useAtomic) atomicAdd(&Yf[(size_t)m*N + n], vvv);
            else Yf[(size_t)m*N + n] = vvv;
          }
          if (Yh) {
            ush hb = f2bf(vvv);
            size_t idx;
            if (ymode == 1) {              // Q-frag: t=m, h=n>>6, d=n&63
              int d = n & 63;
              idx = (size_t)m*1024 + (size_t)(d>>5)*512 + (size_t)((d>>3)&3)*128
                  + (size_t)(n>>6)*8 + (d&7);
            } else if (ymode == 2) {       // K-frag: key=m, d=n
              int b = m >> 6, kk = m & 63;
              idx = (size_t)b*4096 + (size_t)(kk>>4)*1024 + (size_t)(n>>5)*512
                  + (size_t)((n>>3)&3)*128 + (size_t)(kk&15)*8 + (n&7);
            } else if (ymode == 3) {       // V-frag: key=m, d=n
              int b = m >> 6, kk = m & 63, rem = kk & 31;
              idx = (size_t)b*4096 + (size_t)((kk>>5)*4 + (n>>4))*512
                  + (size_t)((rem>>2)&3)*128 + (size_t)(n&15)*8
                  + (rem&3) + ((rem>>4)&1)*4;
            } else {
              idx = (size_t)m*N + n;
            }
            Yh[idx] = hb;
            if (Yl) Yl[idx] = f2bf(vvv - bf2f(hb));
          }
        }
      }
    }
  if (Ch) {
    float ps[2];
    #pragma unroll
    for (int nt = 0; nt < 2; ++nt) {
      ps[nt] = 0.f;
      #pragma unroll
      for (int mt = 0; mt < 2; ++mt)
        #pragma unroll
        for (int r = 0; r < 4; ++r) ps[nt] += acc[mt][nt][r];
      ps[nt] += __shfl_xor(ps[nt], 16);
      ps[nt] += __shfl_xor(ps[nt], 32);
      if (quad == 0) cent[wm][wn*32 + nt*16 + c16] = ps[nt];
    }
    __syncthreads();
    if (wm == 0 && quad == 0) {
      #pragma unroll
      for (int nt = 0; nt < 2; ++nt) {
        int n = wn*32 + nt*16 + c16;
        float mval = (cent[0][n] + cent[1][n]) * (1.f/64.f);
        ush hb = f2bf(mval);
        ush lb = f2bf(mval - bf2f(hb));
        size_t idx;
        if (!ctrans) {   // K-centroid fragment: cent=cidx, d=n
          idx = (size_t)((cidx>>4)*2 + (n>>5))*512 + (size_t)((n>>3)&3)*128
              + (size_t)(cidx&15)*8 + (n&7);
        } else {         // V-centroid fragment: d=n, c=cidx
          idx = (size_t)(n>>4)*512 + (size_t)(cidx>>3)*128
              + (size_t)(n&15)*8 + (cidx&7);
        }
        Ch[idx] = hb; Cl[idx] = lb;
      }
    }
  }
}

// fused q + k/v/g projections (+ centroid pooling); 608 WGs, XCD-banded
// (R8-validated): XCD k <- by in [4k,4k+4) x all bx.
__global__ __launch_bounds__(256) void gemm_proj(
    const ush* __restrict__ xh, const ush* __restrict__ xl,
    const ush* __restrict__ Wqh, const ush* __restrict__ Wql,
    const ush* __restrict__ Wkh, const ush* __restrict__ Wkl,
    const ush* __restrict__ Wvh, const ush* __restrict__ Wvl,
    const ush* __restrict__ Wgh, const ush* __restrict__ Wgl,
    ush* qbF, ush* qlF, ush* kbF, ush* vbF, float* gpj,
    ush* kcF, ush* kcFl, ush* vtF, ush* vtFl, int K)
{
  __shared__ ush Ash[2048], Asl[2048], Bsh[2048], Bsl[2048];  // [64][32] lin
  __shared__ float cent[2][64];
  const int o = blockIdx.x;                  // 0..607
  const int s = (o & 7) * 76 + (o >> 3);     // chunked: XCD gets contiguous s
  const int local = s % 76;
  const int by = 4 * (s / 76) + local / 19;  // 0..31
  const int bx = local % 19;                 // 0..18
  if (bx < 16) {
    gemm64_body(nullptr, xh, xl, Wqh, Wql, nullptr, qbF, qlF, 1, 0,
                nullptr, nullptr, 0, 0, nullptr,
                DM, K, 0, K, by*64, bx*64, Ash, Asl, Bsh, Bsl);
  } else if (bx == 16) {
    gemm64_body(nullptr, xh, xl, Wkh, Wkl, nullptr, kbF, nullptr, 2, 0,
                kcF, kcFl, 0, by, cent,
                HD, K, 0, K, by*64, 0, Ash, Asl, Bsh, Bsl);
  } else if (bx == 17) {
    gemm64_body(nullptr, xh, xl, Wvh, Wvl, nullptr, vbF, nullptr, 3, 0,
                vtF, vtFl, 1, by, cent,
                HD, K, 0, K, by*64, 0, Ash, Asl, Bsh, Bsl);
  } else {
    // G path N=48: B rows 48-63 read past Wgh/Wgl logical end into adjacent
    // workspace (no fault); garbage affects only discarded cols (MFMA output
    // col j depends only on B row j).
    gemm64_body(nullptr, xh, xl, Wgh, Wgl, gpj, nullptr, nullptr, 0, 0,
                nullptr, nullptr, 0, 0, nullptr,
                48, K, 0, K, by*64, 0, Ash, Asl, Bsh, Bsl);
  }
}

// out-projection: A = f32 with inline split (thread-staged); SPLIT-K=2 via
// f32 atomics. 1024 WGs = 8 x 128, XCD-banded (R8-validated).
__global__ __launch_bounds__(256) void gemm_out_sk(
    const float* __restrict__ Af,
    const ush* __restrict__ Wh, const ush* __restrict__ Wl,
    float* Yf, int N, int K)
{
  __shared__ ush Ash[2048], Asl[2048], Bsh[2048], Bsl[2048];
  const int o = blockIdx.x;                  // 0..1023
  const int s = (o & 7) * 128 + (o >> 3);
  const int kz = s >> 9;                     // 0..1
  const int rem = s & 511;
  const int by = rem >> 4;                   // 0..31
  const int bx = rem & 15;                   // 0..15
  const int kHalf = K >> 1;
  const int kStart = kz * kHalf;
  gemm64_body(Af, nullptr, nullptr, Wh, Wl, Yf, nullptr, nullptr, 0, 1,
              nullptr, nullptr, 0, 0, nullptr,
              N, K, kStart, kStart + kHalf, by*64, bx*64,
              Ash, Asl, Bsh, Bsl);
}

// ---- compressed attention + top-k; fragment-order coalesced loads -----------
__global__ __launch_bounds__(256) void cmp_attn_mfma(
    const ush* __restrict__ qbF, const ush* __restrict__ qlF,
    const ush* __restrict__ kcF, const ush* __restrict__ kcFl,
    const ush* __restrict__ vtF, const ush* __restrict__ vtFl,
    float* __restrict__ ocmp, int* __restrict__ blkp)
{
  __shared__ float Pls[4][16][36];
  const int tid = threadIdx.x, w = tid >> 6, lane = tid & 63;
  const int quad = lane >> 4, c16 = lane & 15;
  const int t = blockIdx.x * 4 + w;

  const ush* qt = qbF + (size_t)t*DM + lane*8;
  const ush* ql = qlF + (size_t)t*DM + lane*8;
  bf16x8 qah0 = *(const bf16x8*)(qt);
  bf16x8 qah1 = *(const bf16x8*)(qt + 512);
  bf16x8 qal0 = *(const bf16x8*)(ql);
  bf16x8 qal1 = *(const bf16x8*)(ql + 512);

  f32x4 s[2];
  #pragma unroll
  for (int nh = 0; nh < 2; ++nh) {
    bf16x8 kh0 = *(const bf16x8*)(kcF  + (nh*2+0)*512 + lane*8);
    bf16x8 kh1 = *(const bf16x8*)(kcF  + (nh*2+1)*512 + lane*8);
    bf16x8 kl0 = *(const bf16x8*)(kcFl + (nh*2+0)*512 + lane*8);
    bf16x8 kl1 = *(const bf16x8*)(kcFl + (nh*2+1)*512 + lane*8);
    f32x4 acc = {0.f, 0.f, 0.f, 0.f};
    acc = __builtin_amdgcn_mfma_f32_16x16x32_bf16(qah0, kh0, acc, 0, 0, 0);
    acc = __builtin_amdgcn_mfma_f32_16x16x32_bf16(qah1, kh1, acc, 0, 0, 0);
    acc = __builtin_amdgcn_mfma_f32_16x16x32_bf16(qah0, kl0, acc, 0, 0, 0);
    acc = __builtin_amdgcn_mfma_f32_16x16x32_bf16(qah1, kl1, acc, 0, 0, 0);
    acc = __builtin_amdgcn_mfma_f32_16x16x32_bf16(qal0, kh0, acc, 0, 0, 0);
    acc = __builtin_amdgcn_mfma_f32_16x16x32_bf16(qal1, kh1, acc, 0, 0, 0);
    s[nh] = acc;
  }

  const int nvis = (t + 1) >> 6;
  const bool visA = (c16 < nvis), visB = (16 + c16 < nvis);
  float p[2][4];
  float iA = 0.f, iB = 0.f;
  #pragma unroll
  for (int r = 0; r < 4; ++r) {
    float sA = s[0][r] * 0.125f, sB = s[1][r] * 0.125f;
    float m = fmaxf(visA ? sA : -INFINITY, visB ? sB : -INFINITY);
    #pragma unroll
    for (int off = 1; off < 16; off <<= 1) m = fmaxf(m, __shfl_xor(m, off));
    float eA = visA ? __expf(sA - m) : 0.f;
    float eB = visB ? __expf(sB - m) : 0.f;
    float l = eA + eB;
    #pragma unroll
    for (int off = 1; off < 16; off <<= 1) l += __shfl_xor(l, off);
    float inv = (l > 0.f) ? 1.f / l : 0.f;
    p[0][r] = eA * inv; p[1][r] = eB * inv;
    iA += p[0][r]; iB += p[1][r];
  }
  iA += __shfl_xor(iA, 16); iA += __shfl_xor(iA, 32);
  iB += __shfl_xor(iB, 16); iB += __shfl_xor(iB, 32);

  #pragma unroll
  for (int nh = 0; nh < 2; ++nh)
    #pragma unroll
    for (int r = 0; r < 4; ++r)
      Pls[w][quad*4 + r][nh*16 + c16] = p[nh][r];

  {
    const int cur = t >> 6;
    float a;
    if (lane < 16) a = iA;
    else if (lane < 32) a = iB;
    else a = -INFINITY;
    if (lane < 32) {
      if (lane > cur) a = NEGF;
      if (lane == 0 || lane == cur) a = INFINITY;
    }
    for (int sidx = 0; sidx < S_SEL; ++sidx) {
      float bv = a; int bi = lane;
      #pragma unroll
      for (int off = 1; off < 64; off <<= 1) {
        float ov = __shfl_xor(bv, off); int oi = __shfl_xor(bi, off);
        if (ov > bv || (ov == bv && oi < bi)) { bv = ov; bi = oi; }
      }
      if (lane == 0) blkp[t*S_SEL + sidx] = bi;
      if (lane == bi) a = -INFINITY;
    }
  }
  __syncthreads();

  float4 pa = *(const float4*)&Pls[w][c16][quad*8];
  float4 pb = *(const float4*)&Pls[w][c16][quad*8 + 4];
  float pf[8] = {pa.x, pa.y, pa.z, pa.w, pb.x, pb.y, pb.z, pb.w};
  bf16x8 pah, pal;
  #pragma unroll
  for (int j = 0; j < 8; ++j) {
    ush hb = f2bf(pf[j]);
    pah[j] = (short)hb;
    pal[j] = (short)f2bf(pf[j] - bf2f(hb));
  }
  #pragma unroll
  for (int nb = 0; nb < 4; ++nb) {
    bf16x8 vh8 = *(const bf16x8*)(vtF  + nb*512 + lane*8);
    bf16x8 vl8 = *(const bf16x8*)(vtFl + nb*512 + lane*8);
    f32x4 acc = {0.f, 0.f, 0.f, 0.f};
    acc = __builtin_amdgcn_mfma_f32_16x16x32_bf16(pah, vh8, acc, 0, 0, 0);
    acc = __builtin_amdgcn_mfma_f32_16x16x32_bf16(pah, vl8, acc, 0, 0, 0);
    acc = __builtin_amdgcn_mfma_f32_16x16x32_bf16(pal, vh8, acc, 0, 0, 0);
    #pragma unroll
    for (int r = 0; r < 4; ++r)
      ocmp[(size_t)t*DM + (quad*4 + r)*HD + nb*16 + c16] = acc[r];
  }
}

// ---- selected attention: swapped-operand, fragment-order coalesced loads ----
__global__ __launch_bounds__(256) void sel_attn_frag(
    const ush* __restrict__ qbF, const ush* __restrict__ kbF,
    const ush* __restrict__ vbF, const float* __restrict__ gp,
    const int* __restrict__ blkp, float* __restrict__ ocmp_io)
{
  __shared__ float cO2[4][4][16][17];
  __shared__ float cL[4][16];

  const int tid = threadIdx.x, w = tid >> 6, lane = tid & 63;
  const int quad = lane >> 4, c16 = lane & 15;
  const int t = T_TOK - 1 - blockIdx.x;         // heavy tokens first
  const int cur = t >> 6;
  const int nblk = (cur + 1 < S_SEL) ? cur + 1 : S_SEL;

  int myblk = 0;
  if (lane < S_SEL) myblk = blkp[t*S_SEL + lane];
  const int nb_w = (nblk > w) ? (((nblk - 1 - w) >> 2) + 1) : 0;

  const ush* qt = qbF + (size_t)t*DM + lane*8;
  bf16x8 qa0 = *(const bf16x8*)(qt);
  bf16x8 qa1 = *(const bf16x8*)(qt + 512);

  f32x4 accO[4] = {};
  float lacc = 0.f;

  for (int i = 0; i < nb_w; ++i) {
    const int blk = __shfl(myblk, w + (i << 2));
    const int bs = blk * BS;
    const ush* kB = kbF + (size_t)blk * 4096 + lane*8;
    const ush* vB = vbF + (size_t)blk * 4096 + lane*8;

    bf16x8 kf0[4], kf1[4];
    #pragma unroll
    for (int nc = 0; nc < 4; ++nc) {
      kf0[nc] = *(const bf16x8*)(kB + nc*1024);
      kf1[nc] = *(const bf16x8*)(kB + nc*1024 + 512);
    }
    bf16x8 vf[4][2];
    #pragma unroll
    for (int p = 0; p < 2; ++p)
      #pragma unroll
      for (int dn = 0; dn < 4; ++dn)
        vf[dn][p] = *(const bf16x8*)(vB + (p*4 + dn)*512);

    f32x4 sc[4];
    #pragma unroll
    for (int nc = 0; nc < 4; ++nc) {
      f32x4 a = {0.f, 0.f, 0.f, 0.f};
      a = __builtin_amdgcn_mfma_f32_16x16x32_bf16(kf0[nc], qa0, a, 0, 0, 0);
      a = __builtin_amdgcn_mfma_f32_16x16x32_bf16(kf1[nc], qa1, a, 0, 0, 0);
      sc[nc] = a;
    }

    ush pf[16];
    #pragma unroll
    for (int nc = 0; nc < 4; ++nc) {
      const int k0 = bs + nc*16 + quad*4;
      #pragma unroll
      for (int r = 0; r < 4; ++r) {
        float e = (k0 + r <= t) ? __expf(sc[nc][r] * 0.125f) : 0.f;
        lacc += e;
        pf[nc*4 + r] = f2bf(e);
      }
    }
    bf16x8 P01, P23;
    #pragma unroll
    for (int j = 0; j < 8; ++j) {
      P01[j] = (short)pf[j];
      P23[j] = (short)pf[8 + j];
    }

    #pragma unroll
    for (int dn = 0; dn < 4; ++dn) {
      accO[dn] = __builtin_amdgcn_mfma_f32_16x16x32_bf16(vf[dn][0], P01, accO[dn], 0, 0, 0);
      accO[dn] = __builtin_amdgcn_mfma_f32_16x16x32_bf16(vf[dn][1], P23, accO[dn], 0, 0, 0);
    }
  }

  lacc += __shfl_xor(lacc, 16);
  lacc += __shfl_xor(lacc, 32);

  if (quad == 0) cL[w][c16] = lacc;
  #pragma unroll
  for (int dn = 0; dn < 4; ++dn)
    #pragma unroll
    for (int r = 0; r < 4; ++r)
      cO2[w][dn][quad*4 + r][c16] = accO[dn][r];
  __syncthreads();

  #pragma unroll
  for (int i = 0; i < 4; ++i) {
    const int h = i*4 + w;
    float L = cL[0][h] + cL[1][h] + cL[2][h] + cL[3][h];
    float O = cO2[0][quad][c16][h] + cO2[1][quad][c16][h]
            + cO2[2][quad][c16][h] + cO2[3][quad][c16][h];
    float ga = gp[(size_t)t*48 + h*3 + 0];
    float gb = gp[(size_t)t*48 + h*3 + 1];
    float gcv = 1.f/(1.f + __expf(-ga));
    float gsv = 1.f/(1.f + __expf(-gb));
    size_t idx = (size_t)t*DM + (size_t)h*HD + lane;
    ocmp_io[idx] = O * gsv / L + ocmp_io[idx] * gcv;
  }
}

extern "C" void kernel_launch(void* const* d_in, const int* in_sizes, int n_in,
                              void* d_out, int out_size, void* d_ws, size_t ws_size,
                              hipStream_t stream)
{
  const float* x  = (const float*)d_in[0];
  const float* Wq = (const float*)d_in[1];
  const float* Wk = (const float*)d_in[2];
  const float* Wv = (const float*)d_in[3];
  const float* Wg = (const float*)d_in[4];
  const float* Wo = (const float*)d_in[5];
  float* out = (float*)d_out;

  float* ws   = (float*)d_ws;
  float* gpj  = ws;                                // 2048*48 f32
  float* ocmp = gpj + (size_t)T_TOK*48;            // 2048*1024 f32 (combined o)
  ush* xh  = (ush*)(ocmp + (size_t)T_TOK*DM);      // 2048*1024
  ush* xl  = xh + (size_t)T_TOK*DM;
  ush* qbF = xl + (size_t)T_TOK*DM;                // Q fragment-order
  ush* qlF = qbF + (size_t)T_TOK*DM;
  ush* kbF = qlF + (size_t)T_TOK*DM;               // K fragment-order (2048*64)
  ush* vbF = kbF + (size_t)T_TOK*HD;               // V fragment-order (2048*64)
  ush* kcF = vbF + (size_t)T_TOK*HD;
  ush* kcFl = kcF + NB*HD;
  ush* vtF = kcFl + NB*HD;
  ush* vtFl = vtF + NB*HD;
  ush* Wqh = vtFl + NB*HD;
  ush* Wql = Wqh + 1048576;
  ush* Wkh = Wql + 1048576;
  ush* Wkl = Wkh + 65536;
  ush* Wvh = Wkl + 65536;
  ush* Wvl = Wvh + 65536;
  ush* Wgh = Wvl + 65536;
  ush* Wgl = Wgh + 49152;
  ush* Woh = Wgl + 49152;
  ush* Wol = Woh + 1048576;
  int* blkp = (int*)(Wol + 1048576);               // 2048*16

  split_w7<<<dim3(2048, 7), 256, 0, stream>>>(Wq, Wk, Wv, Wg, Wo, x,
      Wqh, Wql, Wkh, Wkl, Wvh, Wvl, Wgh, Wgl, Woh, Wol, xh, xl, out);
  gemm_proj<<<608, 256, 0, stream>>>(xh, xl, Wqh, Wql,
      Wkh, Wkl, Wvh, Wvl, Wgh, Wgl, qbF, qlF, kbF, vbF, gpj,
      kcF, kcFl, vtF, vtFl, DM);
  cmp_attn_mfma<<<T_TOK/4, 256, 0, stream>>>(qbF, qlF, kcF, kcFl, vtF, vtFl,
      ocmp, blkp);
  sel_attn_frag<<<T_TOK, 256, 0, stream>>>(qbF, kbF, vbF, gpj, blkp, ocmp);
  gemm_out_sk<<<1024, 256, 0, stream>>>(ocmp, Woh, Wol, out, DM, DM);
}

// Round 11
// 165.411 us; speedup vs baseline: 1.1233x; 1.0073x over previous
//
#include <hip/hip_runtime.h>
#include <math.h>

#define T_TOK 2048
#define DM 1024
#define HQ 16
#define HD 64
#define NB 32
#define BS 64
#define S_SEL 16
#define NEGF (-1e30f)

typedef __attribute__((ext_vector_type(8))) short bf16x8;
typedef __attribute__((ext_vector_type(4))) float f32x4;
typedef unsigned short ush;

#define AS3(p) ((__attribute__((address_space(3))) void*)(p))
#define AS1(p) ((const __attribute__((address_space(1))) void*)(p))

__device__ __forceinline__ ush f2bf(float x) {
  unsigned u = __float_as_uint(x);
  return (ush)((u + 0x7fffu + ((u >> 16) & 1u)) >> 16);
}
__device__ __forceinline__ float bf2f(ush h) {
  return __uint_as_float(((unsigned)h) << 16);
}

// ============================================================================
// R11 = R10 (166.6us best: gload_lds GEMM staging + XCD banding + fragment-
// order attn) + ONE change: sel_attn's epilogue stores ocmp as bf16 hi/lo
// PLANES (och/ocl) instead of f32 — exactly the values gemm_out's inline
// split would compute (bit-identical) — so gemm_out stages A via
// global_load_lds like B. This removes from gemm_out the same ~80-op VALU
// staging chain whose removal in proj gave R10's win (R9 counters: 780GB/s
// fill, 29% VALU = staging-rate-bound).
// ============================================================================

// ---- decompose weights + x into bf16 hi/lo planes; seg 6 zeroes d_out -------
__global__ __launch_bounds__(256) void split_w7(
    const float* __restrict__ s0, const float* __restrict__ s1,
    const float* __restrict__ s2, const float* __restrict__ s3,
    const float* __restrict__ s4, const float* __restrict__ s5,
    ush* h0, ush* l0, ush* h1, ush* l1, ush* h2, ush* l2,
    ush* h3, ush* l3, ush* h4, ush* l4, ush* h5, ush* l5,
    float* __restrict__ zout)
{
  int seg = blockIdx.y;
  if (seg == 6) {
    int i = blockIdx.x * 256 + threadIdx.x;
    if (i < (T_TOK*DM)/4) ((float4*)zout)[i] = make_float4(0.f,0.f,0.f,0.f);
    return;
  }
  const float* srcs[6] = {s0, s1, s2, s3, s4, s5};
  ush* hs[6] = {h0, h1, h2, h3, h4, h5};
  ush* ls[6] = {l0, l1, l2, l3, l4, l5};
  const int ns[6] = {1048576, 65536, 65536, 49152, 1048576, 2097152};
  int i = (blockIdx.x * 256 + threadIdx.x) * 4;
  if (i >= ns[seg]) return;
  float4 v = *(const float4*)(srcs[seg] + i);
  ushort4 hv, lv;
  hv.x = f2bf(v.x); lv.x = f2bf(v.x - bf2f(hv.x));
  hv.y = f2bf(v.y); lv.y = f2bf(v.y - bf2f(hv.y));
  hv.z = f2bf(v.z); lv.z = f2bf(v.z - bf2f(hv.z));
  hv.w = f2bf(v.w); lv.w = f2bf(v.w - bf2f(hv.w));
  *(ushort4*)(hs[seg] + i) = hv;
  *(ushort4*)(ls[seg] + i) = lv;
}

// ---- split-bf16 MFMA GEMM body: Y = A @ W^T, 64x64 tile, BK=32 --------------
// LDS tiles: linear [64][32] ush; LDS(row, slot) holds global slot
// slot^(row&3). A and B both bf16 planes via global_load_lds width=16.
// ymode: 0 = f32/linear, 1 = Q-fragment, 2 = K-fragment, 3 = V-fragment
__device__ __forceinline__ void gemm64_body(
    const ush* __restrict__ Ah_, const ush* __restrict__ Al_,
    const ush* __restrict__ Wh, const ush* __restrict__ Wl,
    float* Yf, ush* Yh, ush* Yl, int ymode, int useAtomic,
    ush* Ch, ush* Cl, int ctrans, int cidx, float (*cent)[64],
    int N, int K, int kStart, int kEnd, int m0, int n0,
    ush* Ash, ush* Asl, ush* Bsh, ush* Bsl)
{
  const int tid = threadIdx.x;
  const int wave = tid >> 6, lane = tid & 63;
  const int quad = lane >> 4, c16 = lane & 15;
  const int wm = wave >> 1, wn = wave & 1;
  // gload staging geometry: wave stages 16 rows; lane -> (row, slot)
  const int srow_l = wave*16 + (lane >> 2);          // 0..63
  const int sslot  = lane & 3;
  const int sw_slot = sslot ^ (srow_l & 3);          // pre-swizzled src slot
  const size_t gsA = (size_t)(m0 + srow_l) * K + sw_slot*8;
  const size_t gsB = (size_t)(n0 + srow_l) * K + sw_slot*8;
  f32x4 acc[2][2] = {};
  for (int k0 = kStart; k0 < kEnd; k0 += 32) {
    __syncthreads();
    __builtin_amdgcn_global_load_lds(AS1(Ah_ + gsA + k0), AS3(Ash + wave*512), 16, 0, 0);
    __builtin_amdgcn_global_load_lds(AS1(Al_ + gsA + k0), AS3(Asl + wave*512), 16, 0, 0);
    __builtin_amdgcn_global_load_lds(AS1(Wh + gsB + k0), AS3(Bsh + wave*512), 16, 0, 0);
    __builtin_amdgcn_global_load_lds(AS1(Wl + gsB + k0), AS3(Bsl + wave*512), 16, 0, 0);
    __syncthreads();
    bf16x8 Ahf[2], Alf[2], Bhf[2], Blf[2];
    const int rslot = (quad ^ (c16 & 3)) * 8;        // swizzled read slot
    #pragma unroll
    for (int mt = 0; mt < 2; ++mt) {
      const int ro = (wm*32 + mt*16 + c16)*32 + rslot;
      Ahf[mt] = *(const bf16x8*)&Ash[ro];
      Alf[mt] = *(const bf16x8*)&Asl[ro];
    }
    #pragma unroll
    for (int nt = 0; nt < 2; ++nt) {
      const int ro = (wn*32 + nt*16 + c16)*32 + rslot;
      Bhf[nt] = *(const bf16x8*)&Bsh[ro];
      Blf[nt] = *(const bf16x8*)&Bsl[ro];
    }
    #pragma unroll
    for (int mt = 0; mt < 2; ++mt)
      #pragma unroll
      for (int nt = 0; nt < 2; ++nt) {
        acc[mt][nt] = __builtin_amdgcn_mfma_f32_16x16x32_bf16(Ahf[mt], Bhf[nt], acc[mt][nt], 0, 0, 0);
        acc[mt][nt] = __builtin_amdgcn_mfma_f32_16x16x32_bf16(Ahf[mt], Blf[nt], acc[mt][nt], 0, 0, 0);
        acc[mt][nt] = __builtin_amdgcn_mfma_f32_16x16x32_bf16(Alf[mt], Bhf[nt], acc[mt][nt], 0, 0, 0);
      }
  }
  #pragma unroll
  for (int mt = 0; mt < 2; ++mt)
    #pragma unroll
    for (int nt = 0; nt < 2; ++nt) {
      int n = n0 + wn*32 + nt*16 + c16;
      if (n < N) {
        #pragma unroll
        for (int r = 0; r < 4; ++r) {
          int m = m0 + wm*32 + mt*16 + quad*4 + r;
          float vvv = acc[mt][nt][r];
          if (Yf) {
            if (useAtomic) atomicAdd(&Yf[(size_t)m*N + n], vvv);
            else Yf[(size_t)m*N + n] = vvv;
          }
          if (Yh) {
            ush hb = f2bf(vvv);
            size_t idx;
            if (ymode == 1) {              // Q-frag: t=m, h=n>>6, d=n&63
              int d = n & 63;
              idx = (size_t)m*1024 + (size_t)(d>>5)*512 + (size_t)((d>>3)&3)*128
                  + (size_t)(n>>6)*8 + (d&7);
            } else if (ymode == 2) {       // K-frag: key=m, d=n
              int b = m >> 6, kk = m & 63;
              idx = (size_t)b*4096 + (size_t)(kk>>4)*1024 + (size_t)(n>>5)*512
                  + (size_t)((n>>3)&3)*128 + (size_t)(kk&15)*8 + (n&7);
            } else if (ymode == 3) {       // V-frag: key=m, d=n
              int b = m >> 6, kk = m & 63, rem = kk & 31;
              idx = (size_t)b*4096 + (size_t)((kk>>5)*4 + (n>>4))*512
                  + (size_t)((rem>>2)&3)*128 + (size_t)(n&15)*8
                  + (rem&3) + ((rem>>4)&1)*4;
            } else {
              idx = (size_t)m*N + n;
            }
            Yh[idx] = hb;
            if (Yl) Yl[idx] = f2bf(vvv - bf2f(hb));
          }
        }
      }
    }
  if (Ch) {
    float ps[2];
    #pragma unroll
    for (int nt = 0; nt < 2; ++nt) {
      ps[nt] = 0.f;
      #pragma unroll
      for (int mt = 0; mt < 2; ++mt)
        #pragma unroll
        for (int r = 0; r < 4; ++r) ps[nt] += acc[mt][nt][r];
      ps[nt] += __shfl_xor(ps[nt], 16);
      ps[nt] += __shfl_xor(ps[nt], 32);
      if (quad == 0) cent[wm][wn*32 + nt*16 + c16] = ps[nt];
    }
    __syncthreads();
    if (wm == 0 && quad == 0) {
      #pragma unroll
      for (int nt = 0; nt < 2; ++nt) {
        int n = wn*32 + nt*16 + c16;
        float mval = (cent[0][n] + cent[1][n]) * (1.f/64.f);
        ush hb = f2bf(mval);
        ush lb = f2bf(mval - bf2f(hb));
        size_t idx;
        if (!ctrans) {   // K-centroid fragment: cent=cidx, d=n
          idx = (size_t)((cidx>>4)*2 + (n>>5))*512 + (size_t)((n>>3)&3)*128
              + (size_t)(cidx&15)*8 + (n&7);
        } else {         // V-centroid fragment: d=n, c=cidx
          idx = (size_t)(n>>4)*512 + (size_t)(cidx>>3)*128
              + (size_t)(n&15)*8 + (cidx&7);
        }
        Ch[idx] = hb; Cl[idx] = lb;
      }
    }
  }
}

// fused q + k/v/g projections (+ centroid pooling); 608 WGs, XCD-banded
// (R8-validated): XCD k <- by in [4k,4k+4) x all bx.
__global__ __launch_bounds__(256) void gemm_proj(
    const ush* __restrict__ xh, const ush* __restrict__ xl,
    const ush* __restrict__ Wqh, const ush* __restrict__ Wql,
    const ush* __restrict__ Wkh, const ush* __restrict__ Wkl,
    const ush* __restrict__ Wvh, const ush* __restrict__ Wvl,
    const ush* __restrict__ Wgh, const ush* __restrict__ Wgl,
    ush* qbF, ush* qlF, ush* kbF, ush* vbF, float* gpj,
    ush* kcF, ush* kcFl, ush* vtF, ush* vtFl, int K)
{
  __shared__ ush Ash[2048], Asl[2048], Bsh[2048], Bsl[2048];  // [64][32] lin
  __shared__ float cent[2][64];
  const int o = blockIdx.x;                  // 0..607
  const int s = (o & 7) * 76 + (o >> 3);     // chunked: XCD gets contiguous s
  const int local = s % 76;
  const int by = 4 * (s / 76) + local / 19;  // 0..31
  const int bx = local % 19;                 // 0..18
  if (bx < 16) {
    gemm64_body(xh, xl, Wqh, Wql, nullptr, qbF, qlF, 1, 0,
                nullptr, nullptr, 0, 0, nullptr,
                DM, K, 0, K, by*64, bx*64, Ash, Asl, Bsh, Bsl);
  } else if (bx == 16) {
    gemm64_body(xh, xl, Wkh, Wkl, nullptr, kbF, nullptr, 2, 0,
                kcF, kcFl, 0, by, cent,
                HD, K, 0, K, by*64, 0, Ash, Asl, Bsh, Bsl);
  } else if (bx == 17) {
    gemm64_body(xh, xl, Wvh, Wvl, nullptr, vbF, nullptr, 3, 0,
                vtF, vtFl, 1, by, cent,
                HD, K, 0, K, by*64, 0, Ash, Asl, Bsh, Bsl);
  } else {
    // G path N=48: B rows 48-63 read past Wgh/Wgl logical end into adjacent
    // workspace (no fault); garbage affects only discarded cols.
    gemm64_body(xh, xl, Wgh, Wgl, gpj, nullptr, nullptr, 0, 0,
                nullptr, nullptr, 0, 0, nullptr,
                48, K, 0, K, by*64, 0, Ash, Asl, Bsh, Bsl);
  }
}

// out-projection: A = bf16 planes (och/ocl, produced by sel_attn's epilogue)
// via global_load_lds — NO VALU in staging. SPLIT-K=2 via f32 atomics.
// 1024 WGs = 8 x 128, XCD-banded (R8-validated).
__global__ __launch_bounds__(256) void gemm_out_sk(
    const ush* __restrict__ Ah, const ush* __restrict__ Al,
    const ush* __restrict__ Wh, const ush* __restrict__ Wl,
    float* Yf, int N, int K)
{
  __shared__ ush Ash[2048], Asl[2048], Bsh[2048], Bsl[2048];
  const int o = blockIdx.x;                  // 0..1023
  const int s = (o & 7) * 128 + (o >> 3);
  const int kz = s >> 9;                     // 0..1
  const int rem = s & 511;
  const int by = rem >> 4;                   // 0..31
  const int bx = rem & 15;                   // 0..15
  const int kHalf = K >> 1;
  const int kStart = kz * kHalf;
  gemm64_body(Ah, Al, Wh, Wl, Yf, nullptr, nullptr, 0, 1,
              nullptr, nullptr, 0, 0, nullptr,
              N, K, kStart, kStart + kHalf, by*64, bx*64,
              Ash, Asl, Bsh, Bsl);
}

// ---- compressed attention + top-k; fragment-order coalesced loads -----------
__global__ __launch_bounds__(256) void cmp_attn_mfma(
    const ush* __restrict__ qbF, const ush* __restrict__ qlF,
    const ush* __restrict__ kcF, const ush* __restrict__ kcFl,
    const ush* __restrict__ vtF, const ush* __restrict__ vtFl,
    float* __restrict__ ocmp, int* __restrict__ blkp)
{
  __shared__ float Pls[4][16][36];
  const int tid = threadIdx.x, w = tid >> 6, lane = tid & 63;
  const int quad = lane >> 4, c16 = lane & 15;
  const int t = blockIdx.x * 4 + w;

  const ush* qt = qbF + (size_t)t*DM + lane*8;
  const ush* ql = qlF + (size_t)t*DM + lane*8;
  bf16x8 qah0 = *(const bf16x8*)(qt);
  bf16x8 qah1 = *(const bf16x8*)(qt + 512);
  bf16x8 qal0 = *(const bf16x8*)(ql);
  bf16x8 qal1 = *(const bf16x8*)(ql + 512);

  f32x4 s[2];
  #pragma unroll
  for (int nh = 0; nh < 2; ++nh) {
    bf16x8 kh0 = *(const bf16x8*)(kcF  + (nh*2+0)*512 + lane*8);
    bf16x8 kh1 = *(const bf16x8*)(kcF  + (nh*2+1)*512 + lane*8);
    bf16x8 kl0 = *(const bf16x8*)(kcFl + (nh*2+0)*512 + lane*8);
    bf16x8 kl1 = *(const bf16x8*)(kcFl + (nh*2+1)*512 + lane*8);
    f32x4 acc = {0.f, 0.f, 0.f, 0.f};
    acc = __builtin_amdgcn_mfma_f32_16x16x32_bf16(qah0, kh0, acc, 0, 0, 0);
    acc = __builtin_amdgcn_mfma_f32_16x16x32_bf16(qah1, kh1, acc, 0, 0, 0);
    acc = __builtin_amdgcn_mfma_f32_16x16x32_bf16(qah0, kl0, acc, 0, 0, 0);
    acc = __builtin_amdgcn_mfma_f32_16x16x32_bf16(qah1, kl1, acc, 0, 0, 0);
    acc = __builtin_amdgcn_mfma_f32_16x16x32_bf16(qal0, kh0, acc, 0, 0, 0);
    acc = __builtin_amdgcn_mfma_f32_16x16x32_bf16(qal1, kh1, acc, 0, 0, 0);
    s[nh] = acc;
  }

  const int nvis = (t + 1) >> 6;
  const bool visA = (c16 < nvis), visB = (16 + c16 < nvis);
  float p[2][4];
  float iA = 0.f, iB = 0.f;
  #pragma unroll
  for (int r = 0; r < 4; ++r) {
    float sA = s[0][r] * 0.125f, sB = s[1][r] * 0.125f;
    float m = fmaxf(visA ? sA : -INFINITY, visB ? sB : -INFINITY);
    #pragma unroll
    for (int off = 1; off < 16; off <<= 1) m = fmaxf(m, __shfl_xor(m, off));
    float eA = visA ? __expf(sA - m) : 0.f;
    float eB = visB ? __expf(sB - m) : 0.f;
    float l = eA + eB;
    #pragma unroll
    for (int off = 1; off < 16; off <<= 1) l += __shfl_xor(l, off);
    float inv = (l > 0.f) ? 1.f / l : 0.f;
    p[0][r] = eA * inv; p[1][r] = eB * inv;
    iA += p[0][r]; iB += p[1][r];
  }
  iA += __shfl_xor(iA, 16); iA += __shfl_xor(iA, 32);
  iB += __shfl_xor(iB, 16); iB += __shfl_xor(iB, 32);

  #pragma unroll
  for (int nh = 0; nh < 2; ++nh)
    #pragma unroll
    for (int r = 0; r < 4; ++r)
      Pls[w][quad*4 + r][nh*16 + c16] = p[nh][r];

  {
    const int cur = t >> 6;
    float a;
    if (lane < 16) a = iA;
    else if (lane < 32) a = iB;
    else a = -INFINITY;
    if (lane < 32) {
      if (lane > cur) a = NEGF;
      if (lane == 0 || lane == cur) a = INFINITY;
    }
    for (int sidx = 0; sidx < S_SEL; ++sidx) {
      float bv = a; int bi = lane;
      #pragma unroll
      for (int off = 1; off < 64; off <<= 1) {
        float ov = __shfl_xor(bv, off); int oi = __shfl_xor(bi, off);
        if (ov > bv || (ov == bv && oi < bi)) { bv = ov; bi = oi; }
      }
      if (lane == 0) blkp[t*S_SEL + sidx] = bi;
      if (lane == bi) a = -INFINITY;
    }
  }
  __syncthreads();

  float4 pa = *(const float4*)&Pls[w][c16][quad*8];
  float4 pb = *(const float4*)&Pls[w][c16][quad*8 + 4];
  float pf[8] = {pa.x, pa.y, pa.z, pa.w, pb.x, pb.y, pb.z, pb.w};
  bf16x8 pah, pal;
  #pragma unroll
  for (int j = 0; j < 8; ++j) {
    ush hb = f2bf(pf[j]);
    pah[j] = (short)hb;
    pal[j] = (short)f2bf(pf[j] - bf2f(hb));
  }
  #pragma unroll
  for (int nb = 0; nb < 4; ++nb) {
    bf16x8 vh8 = *(const bf16x8*)(vtF  + nb*512 + lane*8);
    bf16x8 vl8 = *(const bf16x8*)(vtFl + nb*512 + lane*8);
    f32x4 acc = {0.f, 0.f, 0.f, 0.f};
    acc = __builtin_amdgcn_mfma_f32_16x16x32_bf16(pah, vh8, acc, 0, 0, 0);
    acc = __builtin_amdgcn_mfma_f32_16x16x32_bf16(pah, vl8, acc, 0, 0, 0);
    acc = __builtin_amdgcn_mfma_f32_16x16x32_bf16(pal, vh8, acc, 0, 0, 0);
    #pragma unroll
    for (int r = 0; r < 4; ++r)
      ocmp[(size_t)t*DM + (quad*4 + r)*HD + nb*16 + c16] = acc[r];
  }
}

// ---- selected attention: swapped-operand, fragment-order coalesced loads ----
// Epilogue writes the final blended o as bf16 hi/lo PLANES (och/ocl) — the
// exact values gemm_out's inline split would produce (bit-identical).
__global__ __launch_bounds__(256) void sel_attn_frag(
    const ush* __restrict__ qbF, const ush* __restrict__ kbF,
    const ush* __restrict__ vbF, const float* __restrict__ gp,
    const int* __restrict__ blkp, const float* __restrict__ ocmp_in,
    ush* __restrict__ och, ush* __restrict__ ocl)
{
  __shared__ float cO2[4][4][16][17];
  __shared__ float cL[4][16];

  const int tid = threadIdx.x, w = tid >> 6, lane = tid & 63;
  const int quad = lane >> 4, c16 = lane & 15;
  const int t = T_TOK - 1 - blockIdx.x;         // heavy tokens first
  const int cur = t >> 6;
  const int nblk = (cur + 1 < S_SEL) ? cur + 1 : S_SEL;

  int myblk = 0;
  if (lane < S_SEL) myblk = blkp[t*S_SEL + lane];
  const int nb_w = (nblk > w) ? (((nblk - 1 - w) >> 2) + 1) : 0;

  const ush* qt = qbF + (size_t)t*DM + lane*8;
  bf16x8 qa0 = *(const bf16x8*)(qt);
  bf16x8 qa1 = *(const bf16x8*)(qt + 512);

  f32x4 accO[4] = {};
  float lacc = 0.f;

  for (int i = 0; i < nb_w; ++i) {
    const int blk = __shfl(myblk, w + (i << 2));
    const int bs = blk * BS;
    const ush* kB = kbF + (size_t)blk * 4096 + lane*8;
    const ush* vB = vbF + (size_t)blk * 4096 + lane*8;

    bf16x8 kf0[4], kf1[4];
    #pragma unroll
    for (int nc = 0; nc < 4; ++nc) {
      kf0[nc] = *(const bf16x8*)(kB + nc*1024);
      kf1[nc] = *(const bf16x8*)(kB + nc*1024 + 512);
    }
    bf16x8 vf[4][2];
    #pragma unroll
    for (int p = 0; p < 2; ++p)
      #pragma unroll
      for (int dn = 0; dn < 4; ++dn)
        vf[dn][p] = *(const bf16x8*)(vB + (p*4 + dn)*512);

    f32x4 sc[4];
    #pragma unroll
    for (int nc = 0; nc < 4; ++nc) {
      f32x4 a = {0.f, 0.f, 0.f, 0.f};
      a = __builtin_amdgcn_mfma_f32_16x16x32_bf16(kf0[nc], qa0, a, 0, 0, 0);
      a = __builtin_amdgcn_mfma_f32_16x16x32_bf16(kf1[nc], qa1, a, 0, 0, 0);
      sc[nc] = a;
    }

    ush pf[16];
    #pragma unroll
    for (int nc = 0; nc < 4; ++nc) {
      const int k0 = bs + nc*16 + quad*4;
      #pragma unroll
      for (int r = 0; r < 4; ++r) {
        float e = (k0 + r <= t) ? __expf(sc[nc][r] * 0.125f) : 0.f;
        lacc += e;
        pf[nc*4 + r] = f2bf(e);
      }
    }
    bf16x8 P01, P23;
    #pragma unroll
    for (int j = 0; j < 8; ++j) {
      P01[j] = (short)pf[j];
      P23[j] = (short)pf[8 + j];
    }

    #pragma unroll
    for (int dn = 0; dn < 4; ++dn) {
      accO[dn] = __builtin_amdgcn_mfma_f32_16x16x32_bf16(vf[dn][0], P01, accO[dn], 0, 0, 0);
      accO[dn] = __builtin_amdgcn_mfma_f32_16x16x32_bf16(vf[dn][1], P23, accO[dn], 0, 0, 0);
    }
  }

  lacc += __shfl_xor(lacc, 16);
  lacc += __shfl_xor(lacc, 32);

  if (quad == 0) cL[w][c16] = lacc;
  #pragma unroll
  for (int dn = 0; dn < 4; ++dn)
    #pragma unroll
    for (int r = 0; r < 4; ++r)
      cO2[w][dn][quad*4 + r][c16] = accO[dn][r];
  __syncthreads();

  #pragma unroll
  for (int i = 0; i < 4; ++i) {
    const int h = i*4 + w;
    float L = cL[0][h] + cL[1][h] + cL[2][h] + cL[3][h];
    float O = cO2[0][quad][c16][h] + cO2[1][quad][c16][h]
            + cO2[2][quad][c16][h] + cO2[3][quad][c16][h];
    float ga = gp[(size_t)t*48 + h*3 + 0];
    float gb = gp[(size_t)t*48 + h*3 + 1];
    float gcv = 1.f/(1.f + __expf(-ga));
    float gsv = 1.f/(1.f + __expf(-gb));
    size_t idx = (size_t)t*DM + (size_t)h*HD + lane;
    float v = O * gsv / L + ocmp_in[idx] * gcv;
    ush hb = f2bf(v);
    och[idx] = hb;
    ocl[idx] = f2bf(v - bf2f(hb));
  }
}

extern "C" void kernel_launch(void* const* d_in, const int* in_sizes, int n_in,
                              void* d_out, int out_size, void* d_ws, size_t ws_size,
                              hipStream_t stream)
{
  const float* x  = (const float*)d_in[0];
  const float* Wq = (const float*)d_in[1];
  const float* Wk = (const float*)d_in[2];
  const float* Wv = (const float*)d_in[3];
  const float* Wg = (const float*)d_in[4];
  const float* Wo = (const float*)d_in[5];
  float* out = (float*)d_out;

  float* ws   = (float*)d_ws;
  float* gpj  = ws;                                // 2048*48 f32
  float* ocmp = gpj + (size_t)T_TOK*48;            // 2048*1024 f32 (cmp o)
  ush* xh  = (ush*)(ocmp + (size_t)T_TOK*DM);      // 2048*1024
  ush* xl  = xh + (size_t)T_TOK*DM;
  ush* qbF = xl + (size_t)T_TOK*DM;                // Q fragment-order
  ush* qlF = qbF + (size_t)T_TOK*DM;
  ush* kbF = qlF + (size_t)T_TOK*DM;               // K fragment-order (2048*64)
  ush* vbF = kbF + (size_t)T_TOK*HD;               // V fragment-order (2048*64)
  ush* kcF = vbF + (size_t)T_TOK*HD;
  ush* kcFl = kcF + NB*HD;
  ush* vtF = kcFl + NB*HD;
  ush* vtFl = vtF + NB*HD;
  ush* Wqh = vtFl + NB*HD;
  ush* Wql = Wqh + 1048576;
  ush* Wkh = Wql + 1048576;
  ush* Wkl = Wkh + 65536;
  ush* Wvh = Wkl + 65536;
  ush* Wvl = Wvh + 65536;
  ush* Wgh = Wvl + 65536;
  ush* Wgl = Wgh + 49152;
  ush* Woh = Wgl + 49152;
  ush* Wol = Woh + 1048576;
  int* blkp = (int*)(Wol + 1048576);               // 2048*16
  ush* och = (ush*)(blkp + T_TOK*S_SEL);           // blended o, hi plane
  ush* ocl = och + (size_t)T_TOK*DM;               // blended o, lo plane

  split_w7<<<dim3(2048, 7), 256, 0, stream>>>(Wq, Wk, Wv, Wg, Wo, x,
      Wqh, Wql, Wkh, Wkl, Wvh, Wvl, Wgh, Wgl, Woh, Wol, xh, xl, out);
  gemm_proj<<<608, 256, 0, stream>>>(xh, xl, Wqh, Wql,
      Wkh, Wkl, Wvh, Wvl, Wgh, Wgl, qbF, qlF, kbF, vbF, gpj,
      kcF, kcFl, vtF, vtFl, DM);
  cmp_attn_mfma<<<T_TOK/4, 256, 0, stream>>>(qbF, qlF, kcF, kcFl, vtF, vtFl,
      ocmp, blkp);
  sel_attn_frag<<<T_TOK, 256, 0, stream>>>(qbF, kbF, vbF, gpj, blkp, ocmp,
      och, ocl);
  gemm_out_sk<<<1024, 256, 0, stream>>>(och, ocl, Woh, Wol, out, DM, DM);
}

// Round 12
// 163.572 us; speedup vs baseline: 1.1360x; 1.0112x over previous
//
#include <hip/hip_runtime.h>
#include <math.h>

#define T_TOK 2048
#define DM 1024
#define HQ 16
#define HD 64
#define NB 32
#define BS 64
#define S_SEL 16
#define NEGF (-1e30f)

typedef __attribute__((ext_vector_type(8))) short bf16x8;
typedef __attribute__((ext_vector_type(4))) float f32x4;
typedef unsigned short ush;

#define AS3(p) ((__attribute__((address_space(3))) void*)(p))
#define AS1(p) ((const __attribute__((address_space(1))) void*)(p))

__device__ __forceinline__ ush f2bf(float x) {
  unsigned u = __float_as_uint(x);
  return (ush)((u + 0x7fffu + ((u >> 16) & 1u)) >> 16);
}
__device__ __forceinline__ float bf2f(ush h) {
  return __uint_as_float(((unsigned)h) << 16);
}

// ============================================================================
// R12 = R11 (165.4us: gload_lds staging + XCD banding + fragment-order attn +
// och/ocl planes) + ONE change: the GEMM k-loop becomes a 2-deep LDS
// ping-pong with COUNTED vmcnt across RAW barriers (T3/T4-minimum). R10/R11
// proved staging VALU is not the cost; the remaining per-step cost is the
// __syncthreads-forced vmcnt(0) drain (m97 lesson) x 32 steps. Counted
// vmcnt(4) keeps next-step loads in flight through compute.
// Discipline: every asm waitcnt has "memory" clobber + sched_barrier(0)
// (rule #18); empty memory-asm after each raw s_barrier pins LDS ops.
// ============================================================================

// ---- decompose weights + x into bf16 hi/lo planes; seg 6 zeroes d_out -------
__global__ __launch_bounds__(256) void split_w7(
    const float* __restrict__ s0, const float* __restrict__ s1,
    const float* __restrict__ s2, const float* __restrict__ s3,
    const float* __restrict__ s4, const float* __restrict__ s5,
    ush* h0, ush* l0, ush* h1, ush* l1, ush* h2, ush* l2,
    ush* h3, ush* l3, ush* h4, ush* l4, ush* h5, ush* l5,
    float* __restrict__ zout)
{
  int seg = blockIdx.y;
  if (seg == 6) {
    int i = blockIdx.x * 256 + threadIdx.x;
    if (i < (T_TOK*DM)/4) ((float4*)zout)[i] = make_float4(0.f,0.f,0.f,0.f);
    return;
  }
  const float* srcs[6] = {s0, s1, s2, s3, s4, s5};
  ush* hs[6] = {h0, h1, h2, h3, h4, h5};
  ush* ls[6] = {l0, l1, l2, l3, l4, l5};
  const int ns[6] = {1048576, 65536, 65536, 49152, 1048576, 2097152};
  int i = (blockIdx.x * 256 + threadIdx.x) * 4;
  if (i >= ns[seg]) return;
  float4 v = *(const float4*)(srcs[seg] + i);
  ushort4 hv, lv;
  hv.x = f2bf(v.x); lv.x = f2bf(v.x - bf2f(hv.x));
  hv.y = f2bf(v.y); lv.y = f2bf(v.y - bf2f(hv.y));
  hv.z = f2bf(v.z); lv.z = f2bf(v.z - bf2f(hv.z));
  hv.w = f2bf(v.w); lv.w = f2bf(v.w - bf2f(hv.w));
  *(ushort4*)(hs[seg] + i) = hv;
  *(ushort4*)(ls[seg] + i) = lv;
}

// pipeline sync primitives (rule #18 + m152 discipline)
#define PIPE_WAIT4 do { \
    asm volatile("s_waitcnt vmcnt(4)" ::: "memory"); \
    __builtin_amdgcn_sched_barrier(0); \
    __builtin_amdgcn_s_barrier(); \
    asm volatile("" ::: "memory"); \
  } while (0)
#define PIPE_WAIT0 do { \
    asm volatile("s_waitcnt vmcnt(0)" ::: "memory"); \
    __builtin_amdgcn_sched_barrier(0); \
    __builtin_amdgcn_s_barrier(); \
    asm volatile("" ::: "memory"); \
  } while (0)
#define PIPE_BAR do { \
    asm volatile("s_waitcnt lgkmcnt(0)" ::: "memory"); \
    __builtin_amdgcn_s_barrier(); \
    asm volatile("" ::: "memory"); \
  } while (0)

// ---- split-bf16 MFMA GEMM body: Y = A @ W^T, 64x64 tile, BK=32, 2-deep ------
// LDS: two static buffer sets (0/1), linear [64][32] ush each, slot^(row&3)
// swizzle on BOTH pre-swizzled global source and fragment read.
// ymode: 0 = f32/linear, 1 = Q-fragment, 2 = K-fragment, 3 = V-fragment
__device__ __forceinline__ void gemm64_body(
    const ush* __restrict__ Ah_, const ush* __restrict__ Al_,
    const ush* __restrict__ Wh, const ush* __restrict__ Wl,
    float* Yf, ush* Yh, ush* Yl, int ymode, int useAtomic,
    ush* Ch, ush* Cl, int ctrans, int cidx, float (*cent)[64],
    int N, int K, int kStart, int kEnd, int m0, int n0,
    ush* A0h, ush* A0l, ush* B0h, ush* B0l,
    ush* A1h, ush* A1l, ush* B1h, ush* B1l)
{
  const int tid = threadIdx.x;
  const int wave = tid >> 6, lane = tid & 63;
  const int quad = lane >> 4, c16 = lane & 15;
  const int wm = wave >> 1, wn = wave & 1;
  // gload staging geometry: wave stages 16 rows; lane -> (row, slot)
  const int srow_l = wave*16 + (lane >> 2);          // 0..63
  const int sslot  = lane & 3;
  const int sw_slot = sslot ^ (srow_l & 3);          // pre-swizzled src slot
  const size_t gsA = (size_t)(m0 + srow_l) * K + sw_slot*8;
  const size_t gsB = (size_t)(n0 + srow_l) * K + sw_slot*8;
  f32x4 acc[2][2] = {};

#define ISSUE(BAh,BAl,BBh,BBl,KOFF) do { \
    __builtin_amdgcn_global_load_lds(AS1(Ah_ + gsA + (KOFF)), AS3(BAh + wave*512), 16, 0, 0); \
    __builtin_amdgcn_global_load_lds(AS1(Al_ + gsA + (KOFF)), AS3(BAl + wave*512), 16, 0, 0); \
    __builtin_amdgcn_global_load_lds(AS1(Wh  + gsB + (KOFF)), AS3(BBh + wave*512), 16, 0, 0); \
    __builtin_amdgcn_global_load_lds(AS1(Wl  + gsB + (KOFF)), AS3(BBl + wave*512), 16, 0, 0); \
  } while (0)

#define COMPUTE(BAh,BAl,BBh,BBl) do { \
    bf16x8 Ahf[2], Alf[2], Bhf[2], Blf[2]; \
    const int rslot = (quad ^ (c16 & 3)) * 8; \
    _Pragma("unroll") \
    for (int mt = 0; mt < 2; ++mt) { \
      const int ro = (wm*32 + mt*16 + c16)*32 + rslot; \
      Ahf[mt] = *(const bf16x8*)&BAh[ro]; \
      Alf[mt] = *(const bf16x8*)&BAl[ro]; \
    } \
    _Pragma("unroll") \
    for (int nt = 0; nt < 2; ++nt) { \
      const int ro = (wn*32 + nt*16 + c16)*32 + rslot; \
      Bhf[nt] = *(const bf16x8*)&BBh[ro]; \
      Blf[nt] = *(const bf16x8*)&BBl[ro]; \
    } \
    _Pragma("unroll") \
    for (int mt = 0; mt < 2; ++mt) \
      _Pragma("unroll") \
      for (int nt = 0; nt < 2; ++nt) { \
        acc[mt][nt] = __builtin_amdgcn_mfma_f32_16x16x32_bf16(Ahf[mt], Bhf[nt], acc[mt][nt], 0, 0, 0); \
        acc[mt][nt] = __builtin_amdgcn_mfma_f32_16x16x32_bf16(Ahf[mt], Blf[nt], acc[mt][nt], 0, 0, 0); \
        acc[mt][nt] = __builtin_amdgcn_mfma_f32_16x16x32_bf16(Alf[mt], Bhf[nt], acc[mt][nt], 0, 0, 0); \
      } \
  } while (0)

  // P 32-steps, always even (proj: 32; out split: 16). Pairs of steps with
  // static buffer alternation (no runtime-indexed LDS pointers — rule #20).
  const int P = (kEnd - kStart) >> 5;
  ISSUE(A0h, A0l, B0h, B0l, kStart);
  for (int p = 0; p < P; p += 2) {
    const int k0 = kStart + p*32;
    ISSUE(A1h, A1l, B1h, B1l, k0 + 32);   // prefetch step p+1
    PIPE_WAIT4;                           // my buf0 loads done; all waves sync
    COMPUTE(A0h, A0l, B0h, B0l);
    PIPE_BAR;                             // all waves done reading buf0
    if (p + 2 < P) {
      ISSUE(A0h, A0l, B0h, B0l, k0 + 64); // prefetch step p+2
      PIPE_WAIT4;                         // buf1 ready (its 4 are the oldest)
    } else {
      PIPE_WAIT0;                         // last pair: drain
    }
    COMPUTE(A1h, A1l, B1h, B1l);
    PIPE_BAR;                             // all waves done reading buf1
  }
#undef ISSUE
#undef COMPUTE

  #pragma unroll
  for (int mt = 0; mt < 2; ++mt)
    #pragma unroll
    for (int nt = 0; nt < 2; ++nt) {
      int n = n0 + wn*32 + nt*16 + c16;
      if (n < N) {
        #pragma unroll
        for (int r = 0; r < 4; ++r) {
          int m = m0 + wm*32 + mt*16 + quad*4 + r;
          float vvv = acc[mt][nt][r];
          if (Yf) {
            if (useAtomic) atomicAdd(&Yf[(size_t)m*N + n], vvv);
            else Yf[(size_t)m*N + n] = vvv;
          }
          if (Yh) {
            ush hb = f2bf(vvv);
            size_t idx;
            if (ymode == 1) {              // Q-frag: t=m, h=n>>6, d=n&63
              int d = n & 63;
              idx = (size_t)m*1024 + (size_t)(d>>5)*512 + (size_t)((d>>3)&3)*128
                  + (size_t)(n>>6)*8 + (d&7);
            } else if (ymode == 2) {       // K-frag: key=m, d=n
              int b = m >> 6, kk = m & 63;
              idx = (size_t)b*4096 + (size_t)(kk>>4)*1024 + (size_t)(n>>5)*512
                  + (size_t)((n>>3)&3)*128 + (size_t)(kk&15)*8 + (n&7);
            } else if (ymode == 3) {       // V-frag: key=m, d=n
              int b = m >> 6, kk = m & 63, rem = kk & 31;
              idx = (size_t)b*4096 + (size_t)((kk>>5)*4 + (n>>4))*512
                  + (size_t)((rem>>2)&3)*128 + (size_t)(n&15)*8
                  + (rem&3) + ((rem>>4)&1)*4;
            } else {
              idx = (size_t)m*N + n;
            }
            Yh[idx] = hb;
            if (Yl) Yl[idx] = f2bf(vvv - bf2f(hb));
          }
        }
      }
    }
  if (Ch) {
    float ps[2];
    #pragma unroll
    for (int nt = 0; nt < 2; ++nt) {
      ps[nt] = 0.f;
      #pragma unroll
      for (int mt = 0; mt < 2; ++mt)
        #pragma unroll
        for (int r = 0; r < 4; ++r) ps[nt] += acc[mt][nt][r];
      ps[nt] += __shfl_xor(ps[nt], 16);
      ps[nt] += __shfl_xor(ps[nt], 32);
      if (quad == 0) cent[wm][wn*32 + nt*16 + c16] = ps[nt];
    }
    __syncthreads();
    if (wm == 0 && quad == 0) {
      #pragma unroll
      for (int nt = 0; nt < 2; ++nt) {
        int n = wn*32 + nt*16 + c16;
        float mval = (cent[0][n] + cent[1][n]) * (1.f/64.f);
        ush hb = f2bf(mval);
        ush lb = f2bf(mval - bf2f(hb));
        size_t idx;
        if (!ctrans) {   // K-centroid fragment: cent=cidx, d=n
          idx = (size_t)((cidx>>4)*2 + (n>>5))*512 + (size_t)((n>>3)&3)*128
              + (size_t)(cidx&15)*8 + (n&7);
        } else {         // V-centroid fragment: d=n, c=cidx
          idx = (size_t)(n>>4)*512 + (size_t)(cidx>>3)*128
              + (size_t)(n&15)*8 + (cidx&7);
        }
        Ch[idx] = hb; Cl[idx] = lb;
      }
    }
  }
}

// fused q + k/v/g projections (+ centroid pooling); 608 WGs, XCD-banded
// (R8-validated): XCD k <- by in [4k,4k+4) x all bx.
__global__ __launch_bounds__(256) void gemm_proj(
    const ush* __restrict__ xh, const ush* __restrict__ xl,
    const ush* __restrict__ Wqh, const ush* __restrict__ Wql,
    const ush* __restrict__ Wkh, const ush* __restrict__ Wkl,
    const ush* __restrict__ Wvh, const ush* __restrict__ Wvl,
    const ush* __restrict__ Wgh, const ush* __restrict__ Wgl,
    ush* qbF, ush* qlF, ush* kbF, ush* vbF, float* gpj,
    ush* kcF, ush* kcFl, ush* vtF, ush* vtFl, int K)
{
  __shared__ ush A0h[2048], A0l[2048], B0h[2048], B0l[2048];
  __shared__ ush A1h[2048], A1l[2048], B1h[2048], B1l[2048];
  __shared__ float cent[2][64];
  const int o = blockIdx.x;                  // 0..607
  const int s = (o & 7) * 76 + (o >> 3);     // chunked: XCD gets contiguous s
  const int local = s % 76;
  const int by = 4 * (s / 76) + local / 19;  // 0..31
  const int bx = local % 19;                 // 0..18
  if (bx < 16) {
    gemm64_body(xh, xl, Wqh, Wql, nullptr, qbF, qlF, 1, 0,
                nullptr, nullptr, 0, 0, nullptr,
                DM, K, 0, K, by*64, bx*64,
                A0h, A0l, B0h, B0l, A1h, A1l, B1h, B1l);
  } else if (bx == 16) {
    gemm64_body(xh, xl, Wkh, Wkl, nullptr, kbF, nullptr, 2, 0,
                kcF, kcFl, 0, by, cent,
                HD, K, 0, K, by*64, 0,
                A0h, A0l, B0h, B0l, A1h, A1l, B1h, B1l);
  } else if (bx == 17) {
    gemm64_body(xh, xl, Wvh, Wvl, nullptr, vbF, nullptr, 3, 0,
                vtF, vtFl, 1, by, cent,
                HD, K, 0, K, by*64, 0,
                A0h, A0l, B0h, B0l, A1h, A1l, B1h, B1l);
  } else {
    // G path N=48: B rows 48-63 read past Wgh/Wgl logical end into adjacent
    // workspace (no fault); garbage affects only discarded cols.
    gemm64_body(xh, xl, Wgh, Wgl, gpj, nullptr, nullptr, 0, 0,
                nullptr, nullptr, 0, 0, nullptr,
                48, K, 0, K, by*64, 0,
                A0h, A0l, B0h, B0l, A1h, A1l, B1h, B1l);
  }
}

// out-projection: A = bf16 planes (och/ocl from sel_attn's epilogue) via
// global_load_lds. SPLIT-K=2 via f32 atomics. 1024 WGs, XCD-banded.
__global__ __launch_bounds__(256) void gemm_out_sk(
    const ush* __restrict__ Ah, const ush* __restrict__ Al,
    const ush* __restrict__ Wh, const ush* __restrict__ Wl,
    float* Yf, int N, int K)
{
  __shared__ ush A0h[2048], A0l[2048], B0h[2048], B0l[2048];
  __shared__ ush A1h[2048], A1l[2048], B1h[2048], B1l[2048];
  const int o = blockIdx.x;                  // 0..1023
  const int s = (o & 7) * 128 + (o >> 3);
  const int kz = s >> 9;                     // 0..1
  const int rem = s & 511;
  const int by = rem >> 4;                   // 0..31
  const int bx = rem & 15;                   // 0..15
  const int kHalf = K >> 1;
  const int kStart = kz * kHalf;
  gemm64_body(Ah, Al, Wh, Wl, Yf, nullptr, nullptr, 0, 1,
              nullptr, nullptr, 0, 0, nullptr,
              N, K, kStart, kStart + kHalf, by*64, bx*64,
              A0h, A0l, B0h, B0l, A1h, A1l, B1h, B1l);
}

// ---- compressed attention + top-k; fragment-order coalesced loads -----------
__global__ __launch_bounds__(256) void cmp_attn_mfma(
    const ush* __restrict__ qbF, const ush* __restrict__ qlF,
    const ush* __restrict__ kcF, const ush* __restrict__ kcFl,
    const ush* __restrict__ vtF, const ush* __restrict__ vtFl,
    float* __restrict__ ocmp, int* __restrict__ blkp)
{
  __shared__ float Pls[4][16][36];
  const int tid = threadIdx.x, w = tid >> 6, lane = tid & 63;
  const int quad = lane >> 4, c16 = lane & 15;
  const int t = blockIdx.x * 4 + w;

  const ush* qt = qbF + (size_t)t*DM + lane*8;
  const ush* ql = qlF + (size_t)t*DM + lane*8;
  bf16x8 qah0 = *(const bf16x8*)(qt);
  bf16x8 qah1 = *(const bf16x8*)(qt + 512);
  bf16x8 qal0 = *(const bf16x8*)(ql);
  bf16x8 qal1 = *(const bf16x8*)(ql + 512);

  f32x4 s[2];
  #pragma unroll
  for (int nh = 0; nh < 2; ++nh) {
    bf16x8 kh0 = *(const bf16x8*)(kcF  + (nh*2+0)*512 + lane*8);
    bf16x8 kh1 = *(const bf16x8*)(kcF  + (nh*2+1)*512 + lane*8);
    bf16x8 kl0 = *(const bf16x8*)(kcFl + (nh*2+0)*512 + lane*8);
    bf16x8 kl1 = *(const bf16x8*)(kcFl + (nh*2+1)*512 + lane*8);
    f32x4 acc = {0.f, 0.f, 0.f, 0.f};
    acc = __builtin_amdgcn_mfma_f32_16x16x32_bf16(qah0, kh0, acc, 0, 0, 0);
    acc = __builtin_amdgcn_mfma_f32_16x16x32_bf16(qah1, kh1, acc, 0, 0, 0);
    acc = __builtin_amdgcn_mfma_f32_16x16x32_bf16(qah0, kl0, acc, 0, 0, 0);
    acc = __builtin_amdgcn_mfma_f32_16x16x32_bf16(qah1, kl1, acc, 0, 0, 0);
    acc = __builtin_amdgcn_mfma_f32_16x16x32_bf16(qal0, kh0, acc, 0, 0, 0);
    acc = __builtin_amdgcn_mfma_f32_16x16x32_bf16(qal1, kh1, acc, 0, 0, 0);
    s[nh] = acc;
  }

  const int nvis = (t + 1) >> 6;
  const bool visA = (c16 < nvis), visB = (16 + c16 < nvis);
  float p[2][4];
  float iA = 0.f, iB = 0.f;
  #pragma unroll
  for (int r = 0; r < 4; ++r) {
    float sA = s[0][r] * 0.125f, sB = s[1][r] * 0.125f;
    float m = fmaxf(visA ? sA : -INFINITY, visB ? sB : -INFINITY);
    #pragma unroll
    for (int off = 1; off < 16; off <<= 1) m = fmaxf(m, __shfl_xor(m, off));
    float eA = visA ? __expf(sA - m) : 0.f;
    float eB = visB ? __expf(sB - m) : 0.f;
    float l = eA + eB;
    #pragma unroll
    for (int off = 1; off < 16; off <<= 1) l += __shfl_xor(l, off);
    float inv = (l > 0.f) ? 1.f / l : 0.f;
    p[0][r] = eA * inv; p[1][r] = eB * inv;
    iA += p[0][r]; iB += p[1][r];
  }
  iA += __shfl_xor(iA, 16); iA += __shfl_xor(iA, 32);
  iB += __shfl_xor(iB, 16); iB += __shfl_xor(iB, 32);

  #pragma unroll
  for (int nh = 0; nh < 2; ++nh)
    #pragma unroll
    for (int r = 0; r < 4; ++r)
      Pls[w][quad*4 + r][nh*16 + c16] = p[nh][r];

  {
    const int cur = t >> 6;
    float a;
    if (lane < 16) a = iA;
    else if (lane < 32) a = iB;
    else a = -INFINITY;
    if (lane < 32) {
      if (lane > cur) a = NEGF;
      if (lane == 0 || lane == cur) a = INFINITY;
    }
    for (int sidx = 0; sidx < S_SEL; ++sidx) {
      float bv = a; int bi = lane;
      #pragma unroll
      for (int off = 1; off < 64; off <<= 1) {
        float ov = __shfl_xor(bv, off); int oi = __shfl_xor(bi, off);
        if (ov > bv || (ov == bv && oi < bi)) { bv = ov; bi = oi; }
      }
      if (lane == 0) blkp[t*S_SEL + sidx] = bi;
      if (lane == bi) a = -INFINITY;
    }
  }
  __syncthreads();

  float4 pa = *(const float4*)&Pls[w][c16][quad*8];
  float4 pb = *(const float4*)&Pls[w][c16][quad*8 + 4];
  float pf[8] = {pa.x, pa.y, pa.z, pa.w, pb.x, pb.y, pb.z, pb.w};
  bf16x8 pah, pal;
  #pragma unroll
  for (int j = 0; j < 8; ++j) {
    ush hb = f2bf(pf[j]);
    pah[j] = (short)hb;
    pal[j] = (short)f2bf(pf[j] - bf2f(hb));
  }
  #pragma unroll
  for (int nb = 0; nb < 4; ++nb) {
    bf16x8 vh8 = *(const bf16x8*)(vtF  + nb*512 + lane*8);
    bf16x8 vl8 = *(const bf16x8*)(vtFl + nb*512 + lane*8);
    f32x4 acc = {0.f, 0.f, 0.f, 0.f};
    acc = __builtin_amdgcn_mfma_f32_16x16x32_bf16(pah, vh8, acc, 0, 0, 0);
    acc = __builtin_amdgcn_mfma_f32_16x16x32_bf16(pah, vl8, acc, 0, 0, 0);
    acc = __builtin_amdgcn_mfma_f32_16x16x32_bf16(pal, vh8, acc, 0, 0, 0);
    #pragma unroll
    for (int r = 0; r < 4; ++r)
      ocmp[(size_t)t*DM + (quad*4 + r)*HD + nb*16 + c16] = acc[r];
  }
}

// ---- selected attention: swapped-operand, fragment-order coalesced loads ----
// Epilogue writes the final blended o as bf16 hi/lo PLANES (och/ocl) — the
// exact values gemm_out's inline split would produce (bit-identical).
__global__ __launch_bounds__(256) void sel_attn_frag(
    const ush* __restrict__ qbF, const ush* __restrict__ kbF,
    const ush* __restrict__ vbF, const float* __restrict__ gp,
    const int* __restrict__ blkp, const float* __restrict__ ocmp_in,
    ush* __restrict__ och, ush* __restrict__ ocl)
{
  __shared__ float cO2[4][4][16][17];
  __shared__ float cL[4][16];

  const int tid = threadIdx.x, w = tid >> 6, lane = tid & 63;
  const int quad = lane >> 4, c16 = lane & 15;
  const int t = T_TOK - 1 - blockIdx.x;         // heavy tokens first
  const int cur = t >> 6;
  const int nblk = (cur + 1 < S_SEL) ? cur + 1 : S_SEL;

  int myblk = 0;
  if (lane < S_SEL) myblk = blkp[t*S_SEL + lane];
  const int nb_w = (nblk > w) ? (((nblk - 1 - w) >> 2) + 1) : 0;

  const ush* qt = qbF + (size_t)t*DM + lane*8;
  bf16x8 qa0 = *(const bf16x8*)(qt);
  bf16x8 qa1 = *(const bf16x8*)(qt + 512);

  f32x4 accO[4] = {};
  float lacc = 0.f;

  for (int i = 0; i < nb_w; ++i) {
    const int blk = __shfl(myblk, w + (i << 2));
    const int bs = blk * BS;
    const ush* kB = kbF + (size_t)blk * 4096 + lane*8;
    const ush* vB = vbF + (size_t)blk * 4096 + lane*8;

    bf16x8 kf0[4], kf1[4];
    #pragma unroll
    for (int nc = 0; nc < 4; ++nc) {
      kf0[nc] = *(const bf16x8*)(kB + nc*1024);
      kf1[nc] = *(const bf16x8*)(kB + nc*1024 + 512);
    }
    bf16x8 vf[4][2];
    #pragma unroll
    for (int p = 0; p < 2; ++p)
      #pragma unroll
      for (int dn = 0; dn < 4; ++dn)
        vf[dn][p] = *(const bf16x8*)(vB + (p*4 + dn)*512);

    f32x4 sc[4];
    #pragma unroll
    for (int nc = 0; nc < 4; ++nc) {
      f32x4 a = {0.f, 0.f, 0.f, 0.f};
      a = __builtin_amdgcn_mfma_f32_16x16x32_bf16(kf0[nc], qa0, a, 0, 0, 0);
      a = __builtin_amdgcn_mfma_f32_16x16x32_bf16(kf1[nc], qa1, a, 0, 0, 0);
      sc[nc] = a;
    }

    ush pf[16];
    #pragma unroll
    for (int nc = 0; nc < 4; ++nc) {
      const int k0 = bs + nc*16 + quad*4;
      #pragma unroll
      for (int r = 0; r < 4; ++r) {
        float e = (k0 + r <= t) ? __expf(sc[nc][r] * 0.125f) : 0.f;
        lacc += e;
        pf[nc*4 + r] = f2bf(e);
      }
    }
    bf16x8 P01, P23;
    #pragma unroll
    for (int j = 0; j < 8; ++j) {
      P01[j] = (short)pf[j];
      P23[j] = (short)pf[8 + j];
    }

    #pragma unroll
    for (int dn = 0; dn < 4; ++dn) {
      accO[dn] = __builtin_amdgcn_mfma_f32_16x16x32_bf16(vf[dn][0], P01, accO[dn], 0, 0, 0);
      accO[dn] = __builtin_amdgcn_mfma_f32_16x16x32_bf16(vf[dn][1], P23, accO[dn], 0, 0, 0);
    }
  }

  lacc += __shfl_xor(lacc, 16);
  lacc += __shfl_xor(lacc, 32);

  if (quad == 0) cL[w][c16] = lacc;
  #pragma unroll
  for (int dn = 0; dn < 4; ++dn)
    #pragma unroll
    for (int r = 0; r < 4; ++r)
      cO2[w][dn][quad*4 + r][c16] = accO[dn][r];
  __syncthreads();

  #pragma unroll
  for (int i = 0; i < 4; ++i) {
    const int h = i*4 + w;
    float L = cL[0][h] + cL[1][h] + cL[2][h] + cL[3][h];
    float O = cO2[0][quad][c16][h] + cO2[1][quad][c16][h]
            + cO2[2][quad][c16][h] + cO2[3][quad][c16][h];
    float ga = gp[(size_t)t*48 + h*3 + 0];
    float gb = gp[(size_t)t*48 + h*3 + 1];
    float gcv = 1.f/(1.f + __expf(-ga));
    float gsv = 1.f/(1.f + __expf(-gb));
    size_t idx = (size_t)t*DM + (size_t)h*HD + lane;
    float v = O * gsv / L + ocmp_in[idx] * gcv;
    ush hb = f2bf(v);
    och[idx] = hb;
    ocl[idx] = f2bf(v - bf2f(hb));
  }
}

extern "C" void kernel_launch(void* const* d_in, const int* in_sizes, int n_in,
                              void* d_out, int out_size, void* d_ws, size_t ws_size,
                              hipStream_t stream)
{
  const float* x  = (const float*)d_in[0];
  const float* Wq = (const float*)d_in[1];
  const float* Wk = (const float*)d_in[2];
  const float* Wv = (const float*)d_in[3];
  const float* Wg = (const float*)d_in[4];
  const float* Wo = (const float*)d_in[5];
  float* out = (float*)d_out;

  float* ws   = (float*)d_ws;
  float* gpj  = ws;                                // 2048*48 f32
  float* ocmp = gpj + (size_t)T_TOK*48;            // 2048*1024 f32 (cmp o)
  ush* xh  = (ush*)(ocmp + (size_t)T_TOK*DM);      // 2048*1024
  ush* xl  = xh + (size_t)T_TOK*DM;
  ush* qbF = xl + (size_t)T_TOK*DM;                // Q fragment-order
  ush* qlF = qbF + (size_t)T_TOK*DM;
  ush* kbF = qlF + (size_t)T_TOK*DM;               // K fragment-order (2048*64)
  ush* vbF = kbF + (size_t)T_TOK*HD;               // V fragment-order (2048*64)
  ush* kcF = vbF + (size_t)T_TOK*HD;
  ush* kcFl = kcF + NB*HD;
  ush* vtF = kcFl + NB*HD;
  ush* vtFl = vtF + NB*HD;
  ush* Wqh = vtFl + NB*HD;
  ush* Wql = Wqh + 1048576;
  ush* Wkh = Wql + 1048576;
  ush* Wkl = Wkh + 65536;
  ush* Wvh = Wkl + 65536;
  ush* Wvl = Wvh + 65536;
  ush* Wgh = Wvl + 65536;
  ush* Wgl = Wgh + 49152;
  ush* Woh = Wgl + 49152;
  ush* Wol = Woh + 1048576;
  int* blkp = (int*)(Wol + 1048576);               // 2048*16
  ush* och = (ush*)(blkp + T_TOK*S_SEL);           // blended o, hi plane
  ush* ocl = och + (size_t)T_TOK*DM;               // blended o, lo plane

  split_w7<<<dim3(2048, 7), 256, 0, stream>>>(Wq, Wk, Wv, Wg, Wo, x,
      Wqh, Wql, Wkh, Wkl, Wvh, Wvl, Wgh, Wgl, Woh, Wol, xh, xl, out);
  gemm_proj<<<608, 256, 0, stream>>>(xh, xl, Wqh, Wql,
      Wkh, Wkl, Wvh, Wvl, Wgh, Wgl, qbF, qlF, kbF, vbF, gpj,
      kcF, kcFl, vtF, vtFl, DM);
  cmp_attn_mfma<<<T_TOK/4, 256, 0, stream>>>(qbF, qlF, kcF, kcFl, vtF, vtFl,
      ocmp, blkp);
  sel_attn_frag<<<T_TOK, 256, 0, stream>>>(qbF, kbF, vbF, gpj, blkp, ocmp,
      och, ocl);
  gemm_out_sk<<<1024, 256, 0, stream>>>(och, ocl, Woh, Wol, out, DM, DM);
}